// Round 17
// baseline (164.921 us; speedup 1.0000x reference)
//
#include <hip/hip_runtime.h>
#include <hip/hip_fp16.h>
#include <cstdint>
#include <cstddef>

#define TPB 256
static constexpr float RSQRT_C_F = 0.35355339059327373f;  // 1/sqrt(8)

typedef __attribute__((ext_vector_type(8))) short bf16x8;
typedef __attribute__((ext_vector_type(4))) float f32x4;
typedef __attribute__((ext_vector_type(2))) float f32x2;

#if __has_builtin(__builtin_amdgcn_cvt_pk_f32_fp8) && __has_builtin(__builtin_amdgcn_cvt_pk_fp8_f32)
#define USE_HW_FP8 1
#endif

__device__ __forceinline__ unsigned short f2bf(float f) {
    unsigned u = __float_as_uint(f);
    u += 0x7FFFu + ((u >> 16) & 1u);          // round-to-nearest-even
    return (unsigned short)(u >> 16);
}
__device__ __forceinline__ float bf2f(unsigned short h) {
    return __uint_as_float((unsigned)h << 16);
}
__device__ __forceinline__ float loF(unsigned u) { return __uint_as_float(u << 16); }
__device__ __forceinline__ float hiF(unsigned u) { return __uint_as_float(u); }

// ---- fp8 e4m3 encode/decode (HW path via v_cvt_*, SW fallback) ----
__device__ __forceinline__ unsigned char enc8(float v) {
#ifdef USE_HW_FP8
    return (unsigned char)(__builtin_amdgcn_cvt_pk_fp8_f32(v, v, 0, false) & 0xff);
#else
    unsigned s = (__float_as_uint(v) >> 24) & 0x80u;
    float a = fabsf(v);
    if (a < 0.015625f) {                        // subnormal region (< 2^-6)
        int m = __float2int_rn(a * 512.f);      // 0..8
        return (unsigned char)(s | (unsigned)m);
    }
    if (a > 448.f) return (unsigned char)(s | 0x7e);
    unsigned u = __float_as_uint(a);
    u += 0x7FFFFu + ((u >> 20) & 1u);           // RNE into bit 20
    unsigned e8 = ((u >> 23) & 0xffu) - 120u;
    unsigned m3 = (u >> 20) & 7u;
    if (e8 > 15u) return (unsigned char)(s | 0x7e);
    return (unsigned char)(s | (e8 << 3) | m3);
#endif
}

__device__ __forceinline__ void dec8x8(uint2 v, float* o) {
#ifdef USE_HW_FP8
    f32x2 a = __builtin_amdgcn_cvt_pk_f32_fp8((int)v.x, false);
    f32x2 b = __builtin_amdgcn_cvt_pk_f32_fp8((int)v.x, true);
    f32x2 c = __builtin_amdgcn_cvt_pk_f32_fp8((int)v.y, false);
    f32x2 d = __builtin_amdgcn_cvt_pk_f32_fp8((int)v.y, true);
    o[0] = a.x; o[1] = a.y; o[2] = b.x; o[3] = b.y;
    o[4] = c.x; o[5] = c.y; o[6] = d.x; o[7] = d.y;
#else
    unsigned w[2] = {v.x, v.y};
    #pragma unroll
    for (int i = 0; i < 8; i++) {
        unsigned bb = (w[i >> 2] >> ((i & 3) * 8)) & 0xffu;
        unsigned short hs = (unsigned short)(((bb & 0x80u) << 8) | ((bb & 0x7fu) << 7));
        __half h = *reinterpret_cast<__half*>(&hs);   // e4m3 bits in f16 slot => val/256
        o[i] = 256.f * __half2float(h);
    }
#endif
}

// Wbig element (i = input row 0..63, col = fused output col 0..319), on the fly
__device__ __forceinline__ float wbig_elem(const float* __restrict__ Wq,
                                           const float* __restrict__ Wk,
                                           const float* __restrict__ Wm,
                                           const float* __restrict__ Watt0,
                                           const float* __restrict__ Watt1,
                                           const float* __restrict__ Wmsg0,
                                           const float* __restrict__ Wmsg1,
                                           const float* __restrict__ prior0,
                                           const float* __restrict__ prior1,
                                           int i, int col) {
    if (col < 64) return Wq[i * 64 + col];
    int j = col - 64, set = j >> 6, l = j & 63, h = l >> 3, lc = l & 7;
    const float* Win = (set < 2) ? Wk : Wm;
    const float* T = (set == 0) ? Watt0 : (set == 1) ? Watt1 : (set == 2) ? Wmsg0 : Wmsg1;
    float scale = (set == 0) ? prior0[h] * RSQRT_C_F
                : (set == 1) ? prior1[h] * RSQRT_C_F : 1.f;
    float acc = 0.f;
    #pragma unroll
    for (int c = 0; c < 8; c++) acc += Win[i * 64 + h * 8 + c] * T[h * 64 + c * 8 + lc];
    return acc * scale;
}

// ---------------------------------------------------------------------------
// setup_kernel (32 blocks): blocks 0-11 pack Wpack/Wapack (direct-compute, no
// Wbig round trip); blocks 12-13 build bbig[320]; blocks 14-31 zero sub.
// ---------------------------------------------------------------------------
__global__ void setup_kernel(const float* __restrict__ Wq, const float* __restrict__ bq,
                             const float* __restrict__ Wk, const float* __restrict__ bk,
                             const float* __restrict__ Wm, const float* __restrict__ bm,
                             const float* __restrict__ Watt0, const float* __restrict__ prior0,
                             const float* __restrict__ Watt1, const float* __restrict__ prior1,
                             const float* __restrict__ Wmsg0, const float* __restrict__ Wmsg1,
                             const float* __restrict__ Wa,
                             float* __restrict__ bbig,
                             unsigned short* __restrict__ Wpack,
                             unsigned short* __restrict__ Wapack,
                             int4* __restrict__ subzero, int n4) {
    const int b = blockIdx.x, t = threadIdx.x;
    if (b < 12) {
        int p = b * TPB + t;
        if (p >= 48 * 64) return;
        bool isWa = (p >= 40 * 64);
        int pl = isWa ? p - 40 * 64 : p;
        int lane = pl & 63, ctkt = pl >> 6;
        int ct = ctkt >> 1, kt = ctkt & 1;
        int kbase = kt * 32 + (lane >> 4) * 8;
        int col = ct * 16 + (lane & 15);
        unsigned short h[8];
        if (isWa) {
            #pragma unroll
            for (int j = 0; j < 8; j++) h[j] = f2bf(Wa[(size_t)(kbase + j) * 64 + col]);
        } else {
            #pragma unroll
            for (int j = 0; j < 8; j++)
                h[j] = f2bf(wbig_elem(Wq, Wk, Wm, Watt0, Watt1, Wmsg0, Wmsg1,
                                      prior0, prior1, kbase + j, col));
        }
        uint4 pk;
        pk.x = (unsigned)h[0] | ((unsigned)h[1] << 16);
        pk.y = (unsigned)h[2] | ((unsigned)h[3] << 16);
        pk.z = (unsigned)h[4] | ((unsigned)h[5] << 16);
        pk.w = (unsigned)h[6] | ((unsigned)h[7] << 16);
        unsigned short* dst = isWa ? Wapack : Wpack;
        *(uint4*)&dst[(size_t)pl * 8] = pk;
    } else if (b < 14) {
        int col = (b - 12) * TPB + t;
        if (col >= 320) return;
        float v;
        if (col < 64) {
            v = bq[col];
        } else {
            int j = col - 64, set = j >> 6, l = j & 63, h = l >> 3, lc = l & 7;
            const float* bin = (set < 2) ? bk : bm;
            const float* T = (set == 0) ? Watt0 : (set == 1) ? Watt1 : (set == 2) ? Wmsg0 : Wmsg1;
            float scale = (set == 0) ? prior0[h] * RSQRT_C_F
                        : (set == 1) ? prior1[h] * RSQRT_C_F : 1.f;
            float acc = 0.f;
            #pragma unroll
            for (int c = 0; c < 8; c++) acc += bin[h * 8 + c] * T[h * 64 + c * 8 + lc];
            v = acc * scale;
        }
        bbig[col] = v;
    } else {
        int i = (b - 14) * TPB + t;
        int stride = 18 * TPB;
        for (; i < n4; i += stride) subzero[i] = int4{0, 0, 0, 0};
    }
}

// ---------------------------------------------------------------------------
// hist, 4 independent edges per thread. Bucket = (e>>8)&7 matches scatter.
// ---------------------------------------------------------------------------
__global__ void hist_kernel(const int* __restrict__ dst0, const int* __restrict__ dst1,
                            int* __restrict__ sub, int* __restrict__ rank,
                            int E0, int Etot, int N) {
    const int gid = blockIdx.x * TPB + threadIdx.x;
    const int S = gridDim.x * TPB;
    #pragma unroll
    for (int k = 0; k < 4; k++) {
        int e = gid + k * S;
        if (e < Etot) {
            int d = (e < E0) ? dst0[e] : dst1[e - E0];
            d = min(max(d, 0), N - 1);
            rank[e] = atomicAdd(&sub[((e >> 8) & 7) * N + d], 1);
        }
    }
}

// ---- scan1 (sumsub fused): reads sub counts, writes exclusive bases + offsets ----
__global__ void scan1(int* __restrict__ sub, int* __restrict__ offsets,
                      int* __restrict__ blocksums, int n) {
    __shared__ int sums[TPB];
    int b = blockIdx.x, t = threadIdx.x;
    int base = b * 1024 + t * 4;
    int cnt[4];
    #pragma unroll
    for (int i = 0; i < 4; i++) {
        int d = base + i;
        int s = 0;
        if (d < n) {
            #pragma unroll
            for (int bb = 0; bb < 8; bb++) {
                int v = sub[bb * n + d];
                sub[bb * n + d] = s;     // exclusive prefix base
                s += v;
            }
        }
        cnt[i] = s;
    }
    int local = cnt[0] + cnt[1] + cnt[2] + cnt[3];
    sums[t] = local;
    __syncthreads();
    for (int off = 1; off < TPB; off <<= 1) {
        int add = (t >= off) ? sums[t - off] : 0;
        __syncthreads();
        sums[t] += add;
        __syncthreads();
    }
    int excl = sums[t] - local;
    if (base + 0 < n) offsets[base + 0] = excl;
    if (base + 1 < n) offsets[base + 1] = excl + cnt[0];
    if (base + 2 < n) offsets[base + 2] = excl + cnt[0] + cnt[1];
    if (base + 3 < n) offsets[base + 3] = excl + cnt[0] + cnt[1] + cnt[2];
    if (t == TPB - 1) blocksums[b] = sums[TPB - 1];
}

// scan3 with scan2 INLINED (each block redundantly scans raw blocksums in LDS)
// + fused addoff: finalize offsets AND fold them into the 8 sub bases.
__global__ void scan3(int* __restrict__ offsets, const int* __restrict__ blocksums,
                      int* __restrict__ sub, int n, int Etot, int nb) {
    __shared__ int s[TPB];
    __shared__ int excl[TPB];
    int t = threadIdx.x;
    int v = (t < nb) ? blocksums[t] : 0;
    s[t] = v;
    __syncthreads();
    for (int off = 1; off < TPB; off <<= 1) {
        int add = (t >= off) ? s[t - off] : 0;
        __syncthreads();
        s[t] += add;
        __syncthreads();
    }
    excl[t] = s[t] - v;   // exclusive scan of blocksums
    __syncthreads();
    int i = blockIdx.x * TPB + t;
    if (i < n) {
        int vv = offsets[i] + excl[i >> 10];
        offsets[i] = vv;
        #pragma unroll
        for (int b = 0; b < 8; b++) sub[b * n + i] += vv;
    }
    if (i == n) offsets[n] = Etot;
}

// scatter WITHOUT atomics, 4 edges per thread:
// pos = sub_abs[(e>>8)&7][d] + rank[e]
__global__ void scatter_kernel(const int* __restrict__ src0, const int* __restrict__ dst0,
                               const int* __restrict__ src1, const int* __restrict__ dst1,
                               const int* __restrict__ sub,
                               const int* __restrict__ rank, unsigned* __restrict__ records,
                               int E0, int Etot, int N) {
    const int gid = blockIdx.x * TPB + threadIdx.x;
    const int S = gridDim.x * TPB;
    #pragma unroll
    for (int k = 0; k < 4; k++) {
        int e = gid + k * S;
        if (e < Etot) {
            int s, d, setbit;
            if (e < E0) { s = src0[e]; d = dst0[e]; setbit = 0; }
            else        { s = src1[e - E0]; d = dst1[e - E0]; setbit = 1; }
            d = min(max(d, 0), N - 1);
            int pos = sub[((e >> 8) & 7) * N + d] + rank[e];
            pos = min(max(pos, 0), Etot - 1);
            records[pos] = (unsigned)s | ((unsigned)setbit << 24);
        }
    }
}

// ---------------------------------------------------------------------------
// MFMA projection, 128 rows/block: each wave computes TWO 16-row stripes
// (rowbase, rowbase+64) sharing the same B fragments (halves Wpack traffic
// and block count). q (bf16) + km (fp8 e4m3, plane layout, coalesced).
// ---------------------------------------------------------------------------
__global__ __launch_bounds__(TPB) void proj_mfma(const float* __restrict__ x,
                                                 const unsigned short* __restrict__ Wpack,
                                                 const float* __restrict__ bbig,
                                                 unsigned short* __restrict__ qbuf,
                                                 unsigned char* __restrict__ kmbuf8,
                                                 int N) {
    const int lane = threadIdx.x & 63;
    const int wv = threadIdx.x >> 6;
    const int rb0 = blockIdx.x * 128 + wv * 16;
    const int rb1 = rb0 + 64;
    const int arow0 = min(rb0 + (lane & 15), N - 1);
    const int arow1 = min(rb1 + (lane & 15), N - 1);
    const int kbase = (lane >> 4) * 8;

    bf16x8 afA[2], afB[2];
    #pragma unroll
    for (int kt = 0; kt < 2; kt++) {
        const float* xp = x + (size_t)arow0 * 64 + kt * 32 + kbase;
        float4 v0 = *(const float4*)xp;
        float4 v1 = *(const float4*)(xp + 4);
        bf16x8 a;
        a[0] = (short)f2bf(v0.x); a[1] = (short)f2bf(v0.y);
        a[2] = (short)f2bf(v0.z); a[3] = (short)f2bf(v0.w);
        a[4] = (short)f2bf(v1.x); a[5] = (short)f2bf(v1.y);
        a[6] = (short)f2bf(v1.z); a[7] = (short)f2bf(v1.w);
        afA[kt] = a;
        const float* xq = x + (size_t)arow1 * 64 + kt * 32 + kbase;
        float4 w0 = *(const float4*)xq;
        float4 w1 = *(const float4*)(xq + 4);
        bf16x8 b;
        b[0] = (short)f2bf(w0.x); b[1] = (short)f2bf(w0.y);
        b[2] = (short)f2bf(w0.z); b[3] = (short)f2bf(w0.w);
        b[4] = (short)f2bf(w1.x); b[5] = (short)f2bf(w1.y);
        b[6] = (short)f2bf(w1.z); b[7] = (short)f2bf(w1.w);
        afB[kt] = b;
    }

    const int colq = lane & 15;
    const int rgrp = (lane >> 4) * 4;

    for (int ct = 0; ct < 20; ct++) {
        bf16x8 b0 = *(const bf16x8*)(Wpack + ((size_t)(ct * 2 + 0) * 64 + lane) * 8);
        bf16x8 b1 = *(const bf16x8*)(Wpack + ((size_t)(ct * 2 + 1) * 64 + lane) * 8);
        f32x4 accA = {0.f, 0.f, 0.f, 0.f};
        accA = __builtin_amdgcn_mfma_f32_16x16x32_bf16(afA[0], b0, accA, 0, 0, 0);
        accA = __builtin_amdgcn_mfma_f32_16x16x32_bf16(afA[1], b1, accA, 0, 0, 0);
        f32x4 accB = {0.f, 0.f, 0.f, 0.f};
        accB = __builtin_amdgcn_mfma_f32_16x16x32_bf16(afB[0], b0, accB, 0, 0, 0);
        accB = __builtin_amdgcn_mfma_f32_16x16x32_bf16(afB[1], b1, accB, 0, 0, 0);
        const int col = ct * 16 + colq;
        const float bv = bbig[col];
        if (ct < 4) {
            #pragma unroll
            for (int r = 0; r < 4; r++) {
                int row = rb0 + rgrp + r;
                if (row < N) qbuf[(size_t)row * 64 + col] = f2bf(accA[r] + bv);
                int row2 = rb1 + rgrp + r;
                if (row2 < N) qbuf[(size_t)row2 * 64 + col] = f2bf(accB[r] + bv);
            }
        } else {
            const int cm = col - 64;   // 0..255, consecutive across lanes
            #pragma unroll
            for (int r = 0; r < 4; r++) {
                int row = rb0 + rgrp + r;
                if (row < N) kmbuf8[(size_t)row * 256 + cm] = enc8(accA[r] + bv);
                int row2 = rb1 + rgrp + r;
                if (row2 < N) kmbuf8[(size_t)row2 * 256 + cm] = enc8(accB[r] + bv);
            }
        }
    }
}

// ---------------------------------------------------------------------------
// Pool (fp8 gathers): one 8-lane group per receiver (wave = 8 receivers).
// lane = (g, j). Fully lane-local; per edge the 8 lanes read ONE 64B k-line
// + ONE 64B m-line. No online max (scores O(0.1); fminf guards; softmax
// shift-invariance). Unroll x2 for load ILP.
// ---------------------------------------------------------------------------
__global__ __launch_bounds__(TPB) void pool_kernel(const unsigned short* __restrict__ qbuf,
                                                   const unsigned char* __restrict__ kmbuf8,
                                                   const unsigned* __restrict__ records,
                                                   const int* __restrict__ offsets,
                                                   unsigned short* __restrict__ pooledN,
                                                   int N) {
    const int lane = threadIdx.x & 63;
    const int j = lane & 7;
    const int r = ((blockIdx.x * TPB + threadIdx.x) >> 6) * 8 + (lane >> 3);
    if (r >= N) return;
    const int beg = offsets[r], end = offsets[r + 1];

    uint4 qv = *(const uint4*)(qbuf + (size_t)r * 64 + (j << 3));
    float qa0 = loF(qv.x), qa1 = hiF(qv.x), qa2 = loF(qv.y), qa3 = hiF(qv.y);
    float qa4 = loF(qv.z), qa5 = hiF(qv.z), qa6 = loF(qv.w), qa7 = hiF(qv.w);

    float d_run = 0.f;
    float p0 = 0.f, p1 = 0.f, p2 = 0.f, p3 = 0.f, p4 = 0.f, p5 = 0.f, p6 = 0.f, p7 = 0.f;

#define EDGE(T) {                                                              \
        unsigned rec = records[T];                                             \
        size_t base = ((size_t)(rec & 0xFFFFFFu) << 8) + (((rec >> 24) & 1u) << 6) + (j << 3); \
        uint2 kv = *(const uint2*)(kmbuf8 + base);                             \
        uint2 mv = *(const uint2*)(kmbuf8 + base + 128);                       \
        float kf[8], mf[8];                                                    \
        dec8x8(kv, kf); dec8x8(mv, mf);                                        \
        float s = kf[0] * qa0 + kf[1] * qa1 + kf[2] * qa2 + kf[3] * qa3        \
                + kf[4] * qa4 + kf[5] * qa5 + kf[6] * qa6 + kf[7] * qa7;       \
        float c = __expf(fminf(s, 60.f));                                      \
        d_run += c;                                                            \
        p0 += c * mf[0]; p1 += c * mf[1]; p2 += c * mf[2]; p3 += c * mf[3];    \
        p4 += c * mf[4]; p5 += c * mf[5]; p6 += c * mf[6]; p7 += c * mf[7];    \
    }

    int t = beg;
    for (; t + 1 < end; t += 2) { EDGE(t); EDGE(t + 1); }
    if (t < end) EDGE(t);
#undef EDGE

    const float inv = (end > beg) ? 1.f / d_run : 0.f;
    uint4 ov;
    ov.x = (unsigned)f2bf(p0 * inv) | ((unsigned)f2bf(p1 * inv) << 16);
    ov.y = (unsigned)f2bf(p2 * inv) | ((unsigned)f2bf(p3 * inv) << 16);
    ov.z = (unsigned)f2bf(p4 * inv) | ((unsigned)f2bf(p5 * inv) << 16);
    ov.w = (unsigned)f2bf(p6 * inv) | ((unsigned)f2bf(p7 * inv) << 16);
    *(uint4*)(pooledN + (size_t)r * 64 + (j << 3)) = ov;
}

// ---------------------------------------------------------------------------
// MFMA final: out = LN( sc*(gelu(pooledN) @ Wa + ba) + (1-sc)*x ).
// ---------------------------------------------------------------------------
__global__ __launch_bounds__(TPB) void final_mfma(const float* __restrict__ x,
                                                  const unsigned short* __restrict__ pooledN,
                                                  const unsigned short* __restrict__ Wapack,
                                                  const float* __restrict__ ba,
                                                  const float* __restrict__ skipw,
                                                  const float* __restrict__ gamma,
                                                  const float* __restrict__ beta,
                                                  float* __restrict__ out, int N) {
    const int lane = threadIdx.x & 63;
    const int wv = threadIdx.x >> 6;
    const int rowbase = blockIdx.x * 64 + wv * 16;
    const int arow = min(rowbase + (lane & 15), N - 1);
    const int kbase = (lane >> 4) * 8;
    const float sc = 1.f / (1.f + __expf(-skipw[0]));

    bf16x8 afrag[2];
    #pragma unroll
    for (int kt = 0; kt < 2; kt++) {
        uint4 pv = *(const uint4*)(pooledN + (size_t)arow * 64 + kt * 32 + kbase);
        float g[8];
        g[0] = loF(pv.x); g[1] = bf2f((unsigned short)(pv.x >> 16));
        g[2] = loF(pv.y); g[3] = bf2f((unsigned short)(pv.y >> 16));
        g[4] = loF(pv.z); g[5] = bf2f((unsigned short)(pv.z >> 16));
        g[6] = loF(pv.w); g[7] = bf2f((unsigned short)(pv.w >> 16));
        bf16x8 a;
        #pragma unroll
        for (int i = 0; i < 8; i++) {
            float gg = 0.5f * g[i] * (1.f + erff(g[i] * 0.70710678118654752f));
            a[i] = (short)f2bf(gg);
        }
        afrag[kt] = a;
    }

    const int colq = lane & 15;
    const int rgrp = (lane >> 4) * 4;

    float o[4][4];   // [ct][r] post-skip values
    #pragma unroll
    for (int ct = 0; ct < 4; ct++) {
        bf16x8 b0 = *(const bf16x8*)(Wapack + ((size_t)(ct * 2 + 0) * 64 + lane) * 8);
        bf16x8 b1 = *(const bf16x8*)(Wapack + ((size_t)(ct * 2 + 1) * 64 + lane) * 8);
        f32x4 acc = {0.f, 0.f, 0.f, 0.f};
        acc = __builtin_amdgcn_mfma_f32_16x16x32_bf16(afrag[0], b0, acc, 0, 0, 0);
        acc = __builtin_amdgcn_mfma_f32_16x16x32_bf16(afrag[1], b1, acc, 0, 0, 0);
        const int col = ct * 16 + colq;
        const float bav = ba[col];
        #pragma unroll
        for (int r = 0; r < 4; r++) {
            int row = min(rowbase + rgrp + r, N - 1);
            float xv = x[(size_t)row * 64 + col];
            o[ct][r] = sc * (acc[r] + bav) + (1.f - sc) * xv;
        }
    }

    #pragma unroll
    for (int r = 0; r < 4; r++) {
        float s1 = o[0][r] + o[1][r] + o[2][r] + o[3][r];
        float s2 = o[0][r] * o[0][r] + o[1][r] * o[1][r]
                 + o[2][r] * o[2][r] + o[3][r] * o[3][r];
        #pragma unroll
        for (int off = 1; off <= 8; off <<= 1) {
            s1 += __shfl_xor(s1, off, 64);
            s2 += __shfl_xor(s2, off, 64);
        }
        float mu = s1 * (1.f / 64.f);
        float var = s2 * (1.f / 64.f) - mu * mu;
        float rs = rsqrtf(var + 1e-3f);
        const int row = rowbase + rgrp + r;
        if (row < N) {
            #pragma unroll
            for (int ct = 0; ct < 4; ct++) {
                const int col = ct * 16 + colq;
                out[(size_t)row * 64 + col] = gamma[col] * (o[ct][r] - mu) * rs + beta[col];
            }
        }
    }
}

extern "C" void kernel_launch(void* const* d_in, const int* in_sizes, int n_in,
                              void* d_out, int out_size, void* d_ws, size_t ws_size,
                              hipStream_t stream) {
    const float* x      = (const float*)d_in[0];
    const int*   src0   = (const int*)d_in[1];
    const int*   dst0   = (const int*)d_in[2];
    const int*   src1   = (const int*)d_in[3];
    const int*   dst1   = (const int*)d_in[4];
    const float* Wk     = (const float*)d_in[5];
    const float* bk     = (const float*)d_in[6];
    const float* Wm     = (const float*)d_in[7];
    const float* bm     = (const float*)d_in[8];
    const float* Wq     = (const float*)d_in[9];
    const float* bq     = (const float*)d_in[10];
    const float* Wa     = (const float*)d_in[11];
    const float* ba     = (const float*)d_in[12];
    const float* Watt0  = (const float*)d_in[13];
    const float* Wmsg0  = (const float*)d_in[14];
    const float* prior0 = (const float*)d_in[15];
    const float* Watt1  = (const float*)d_in[16];
    const float* Wmsg1  = (const float*)d_in[17];
    const float* prior1 = (const float*)d_in[18];
    const float* skipw  = (const float*)d_in[19];
    const float* gamma  = (const float*)d_in[20];
    const float* beta   = (const float*)d_in[21];

    const int N  = in_sizes[0] / 64;
    const int E0 = in_sizes[1];
    const int E1 = in_sizes[3];
    const int Etot = E0 + E1;

    // workspace layout
    float* ws       = (float*)d_ws;
    float* bbig     = ws;                                   // 320 f32
    unsigned short* Wpack  = (unsigned short*)(bbig + 320); // 40*64*8 bf16 (40 KB)
    unsigned short* Wapack = Wpack + 40 * 64 * 8;           // 8*64*8 bf16 (8 KB)
    unsigned short* qbuf   = Wapack + 8 * 64 * 8;           // N*64 bf16
    unsigned short* pooledN = qbuf + (size_t)N * 64;        // N*64 bf16
    unsigned char* kmbuf8  = (unsigned char*)(pooledN + (size_t)N * 64);  // N*256 fp8
    int* sub        = (int*)(kmbuf8 + (size_t)N * 256);     // 8*N (counts -> abs bases)
    int* offsets    = sub + (size_t)8 * N;                  // N+1
    int* blocksums  = offsets + N + 1;                      // <=256
    int* rank       = blocksums + 512;                      // Etot
    unsigned* records = (unsigned*)(rank + Etot);           // Etot

    const int nb1 = (N + 1023) / 1024;                      // <=98 for N=100K
    const int gE4 = (Etot + 4 * TPB - 1) / (4 * TPB);       // 4 edges per thread

    setup_kernel<<<32, TPB, 0, stream>>>(Wq, bq, Wk, bk, Wm, bm, Watt0, prior0,
                                         Watt1, prior1, Wmsg0, Wmsg1, Wa,
                                         bbig, Wpack, Wapack, (int4*)sub, 2 * N);

    proj_mfma<<<(N + 127) / 128, TPB, 0, stream>>>(x, Wpack, bbig, qbuf, kmbuf8, N);

    hist_kernel<<<gE4, TPB, 0, stream>>>(dst0, dst1, sub, rank, E0, Etot, N);

    scan1<<<nb1, TPB, 0, stream>>>(sub, offsets, blocksums, N);
    scan3<<<(N + 1 + TPB - 1) / TPB, TPB, 0, stream>>>(offsets, blocksums, sub, N, Etot, nb1);

    scatter_kernel<<<gE4, TPB, 0, stream>>>(src0, dst0, src1, dst1, sub,
                                            rank, records, E0, Etot, N);

    pool_kernel<<<((size_t)N * 8 + TPB - 1) / TPB, TPB, 0, stream>>>(qbuf, kmbuf8, records,
                                                                     offsets, pooledN, N);

    final_mfma<<<(N + 63) / 64, TPB, 0, stream>>>(x, pooledN, Wapack, ba, skipw,
                                                  gamma, beta, (float*)d_out, N);
}

// Round 18
// 152.812 us; speedup vs baseline: 1.0792x; 1.0792x over previous
//
#include <hip/hip_runtime.h>
#include <hip/hip_fp16.h>
#include <cstdint>
#include <cstddef>

#define TPB 256
static constexpr float RSQRT_C_F = 0.35355339059327373f;  // 1/sqrt(8)

typedef __attribute__((ext_vector_type(8))) short bf16x8;
typedef __attribute__((ext_vector_type(4))) float f32x4;
typedef __attribute__((ext_vector_type(2))) float f32x2;

#if __has_builtin(__builtin_amdgcn_cvt_pk_f32_fp8) && __has_builtin(__builtin_amdgcn_cvt_pk_fp8_f32)
#define USE_HW_FP8 1
#endif

__device__ __forceinline__ unsigned short f2bf(float f) {
    unsigned u = __float_as_uint(f);
    u += 0x7FFFu + ((u >> 16) & 1u);          // round-to-nearest-even
    return (unsigned short)(u >> 16);
}
__device__ __forceinline__ float bf2f(unsigned short h) {
    return __uint_as_float((unsigned)h << 16);
}
__device__ __forceinline__ float loF(unsigned u) { return __uint_as_float(u << 16); }
__device__ __forceinline__ float hiF(unsigned u) { return __uint_as_float(u); }

// ---- fp8 e4m3 encode/decode (HW path via v_cvt_*, SW fallback) ----
__device__ __forceinline__ unsigned char enc8(float v) {
#ifdef USE_HW_FP8
    return (unsigned char)(__builtin_amdgcn_cvt_pk_fp8_f32(v, v, 0, false) & 0xff);
#else
    unsigned s = (__float_as_uint(v) >> 24) & 0x80u;
    float a = fabsf(v);
    if (a < 0.015625f) {                        // subnormal region (< 2^-6)
        int m = __float2int_rn(a * 512.f);      // 0..8
        return (unsigned char)(s | (unsigned)m);
    }
    if (a > 448.f) return (unsigned char)(s | 0x7e);
    unsigned u = __float_as_uint(a);
    u += 0x7FFFFu + ((u >> 20) & 1u);           // RNE into bit 20
    unsigned e8 = ((u >> 23) & 0xffu) - 120u;
    unsigned m3 = (u >> 20) & 7u;
    if (e8 > 15u) return (unsigned char)(s | 0x7e);
    return (unsigned char)(s | (e8 << 3) | m3);
#endif
}

__device__ __forceinline__ void dec8x8(uint2 v, float* o) {
#ifdef USE_HW_FP8
    f32x2 a = __builtin_amdgcn_cvt_pk_f32_fp8((int)v.x, false);
    f32x2 b = __builtin_amdgcn_cvt_pk_f32_fp8((int)v.x, true);
    f32x2 c = __builtin_amdgcn_cvt_pk_f32_fp8((int)v.y, false);
    f32x2 d = __builtin_amdgcn_cvt_pk_f32_fp8((int)v.y, true);
    o[0] = a.x; o[1] = a.y; o[2] = b.x; o[3] = b.y;
    o[4] = c.x; o[5] = c.y; o[6] = d.x; o[7] = d.y;
#else
    unsigned w[2] = {v.x, v.y};
    #pragma unroll
    for (int i = 0; i < 8; i++) {
        unsigned bb = (w[i >> 2] >> ((i & 3) * 8)) & 0xffu;
        unsigned short hs = (unsigned short)(((bb & 0x80u) << 8) | ((bb & 0x7fu) << 7));
        __half h = *reinterpret_cast<__half*>(&hs);   // e4m3 bits in f16 slot => val/256
        o[i] = 256.f * __half2float(h);
    }
#endif
}

// Wbig element (i = input row 0..63, col = fused output col 0..319), on the fly
__device__ __forceinline__ float wbig_elem(const float* __restrict__ Wq,
                                           const float* __restrict__ Wk,
                                           const float* __restrict__ Wm,
                                           const float* __restrict__ Watt0,
                                           const float* __restrict__ Watt1,
                                           const float* __restrict__ Wmsg0,
                                           const float* __restrict__ Wmsg1,
                                           const float* __restrict__ prior0,
                                           const float* __restrict__ prior1,
                                           int i, int col) {
    if (col < 64) return Wq[i * 64 + col];
    int j = col - 64, set = j >> 6, l = j & 63, h = l >> 3, lc = l & 7;
    const float* Win = (set < 2) ? Wk : Wm;
    const float* T = (set == 0) ? Watt0 : (set == 1) ? Watt1 : (set == 2) ? Wmsg0 : Wmsg1;
    float scale = (set == 0) ? prior0[h] * RSQRT_C_F
                : (set == 1) ? prior1[h] * RSQRT_C_F : 1.f;
    float acc = 0.f;
    #pragma unroll
    for (int c = 0; c < 8; c++) acc += Win[i * 64 + h * 8 + c] * T[h * 64 + c * 8 + lc];
    return acc * scale;
}

// ---------------------------------------------------------------------------
// setup_kernel (32 blocks): blocks 0-11 pack Wpack/Wapack (direct-compute);
// blocks 12-13 build bbig[320]; blocks 14-31 zero sub.
// ---------------------------------------------------------------------------
__global__ void setup_kernel(const float* __restrict__ Wq, const float* __restrict__ bq,
                             const float* __restrict__ Wk, const float* __restrict__ bk,
                             const float* __restrict__ Wm, const float* __restrict__ bm,
                             const float* __restrict__ Watt0, const float* __restrict__ prior0,
                             const float* __restrict__ Watt1, const float* __restrict__ prior1,
                             const float* __restrict__ Wmsg0, const float* __restrict__ Wmsg1,
                             const float* __restrict__ Wa,
                             float* __restrict__ bbig,
                             unsigned short* __restrict__ Wpack,
                             unsigned short* __restrict__ Wapack,
                             int4* __restrict__ subzero, int n4) {
    const int b = blockIdx.x, t = threadIdx.x;
    if (b < 12) {
        int p = b * TPB + t;
        if (p >= 48 * 64) return;
        bool isWa = (p >= 40 * 64);
        int pl = isWa ? p - 40 * 64 : p;
        int lane = pl & 63, ctkt = pl >> 6;
        int ct = ctkt >> 1, kt = ctkt & 1;
        int kbase = kt * 32 + (lane >> 4) * 8;
        int col = ct * 16 + (lane & 15);
        unsigned short h[8];
        if (isWa) {
            #pragma unroll
            for (int j = 0; j < 8; j++) h[j] = f2bf(Wa[(size_t)(kbase + j) * 64 + col]);
        } else {
            #pragma unroll
            for (int j = 0; j < 8; j++)
                h[j] = f2bf(wbig_elem(Wq, Wk, Wm, Watt0, Watt1, Wmsg0, Wmsg1,
                                      prior0, prior1, kbase + j, col));
        }
        uint4 pk;
        pk.x = (unsigned)h[0] | ((unsigned)h[1] << 16);
        pk.y = (unsigned)h[2] | ((unsigned)h[3] << 16);
        pk.z = (unsigned)h[4] | ((unsigned)h[5] << 16);
        pk.w = (unsigned)h[6] | ((unsigned)h[7] << 16);
        unsigned short* dst = isWa ? Wapack : Wpack;
        *(uint4*)&dst[(size_t)pl * 8] = pk;
    } else if (b < 14) {
        int col = (b - 12) * TPB + t;
        if (col >= 320) return;
        float v;
        if (col < 64) {
            v = bq[col];
        } else {
            int j = col - 64, set = j >> 6, l = j & 63, h = l >> 3, lc = l & 7;
            const float* bin = (set < 2) ? bk : bm;
            const float* T = (set == 0) ? Watt0 : (set == 1) ? Watt1 : (set == 2) ? Wmsg0 : Wmsg1;
            float scale = (set == 0) ? prior0[h] * RSQRT_C_F
                        : (set == 1) ? prior1[h] * RSQRT_C_F : 1.f;
            float acc = 0.f;
            #pragma unroll
            for (int c = 0; c < 8; c++) acc += bin[h * 8 + c] * T[h * 64 + c * 8 + lc];
            v = acc * scale;
        }
        bbig[col] = v;
    } else {
        int i = (b - 14) * TPB + t;
        int stride = 18 * TPB;
        for (; i < n4; i += stride) subzero[i] = int4{0, 0, 0, 0};
    }
}

// ---------------------------------------------------------------------------
// hist, 4 independent edges per thread. Bucket = (e>>8)&7 matches scatter.
// ---------------------------------------------------------------------------
__global__ void hist_kernel(const int* __restrict__ dst0, const int* __restrict__ dst1,
                            int* __restrict__ sub, int* __restrict__ rank,
                            int E0, int Etot, int N) {
    const int gid = blockIdx.x * TPB + threadIdx.x;
    const int S = gridDim.x * TPB;
    #pragma unroll
    for (int k = 0; k < 4; k++) {
        int e = gid + k * S;
        if (e < Etot) {
            int d = (e < E0) ? dst0[e] : dst1[e - E0];
            d = min(max(d, 0), N - 1);
            rank[e] = atomicAdd(&sub[((e >> 8) & 7) * N + d], 1);
        }
    }
}

// ---- scan1 (sumsub fused): reads sub counts, writes exclusive bases + offsets ----
__global__ void scan1(int* __restrict__ sub, int* __restrict__ offsets,
                      int* __restrict__ blocksums, int n) {
    __shared__ int sums[TPB];
    int b = blockIdx.x, t = threadIdx.x;
    int base = b * 1024 + t * 4;
    int cnt[4];
    #pragma unroll
    for (int i = 0; i < 4; i++) {
        int d = base + i;
        int s = 0;
        if (d < n) {
            #pragma unroll
            for (int bb = 0; bb < 8; bb++) {
                int v = sub[bb * n + d];
                sub[bb * n + d] = s;     // exclusive prefix base
                s += v;
            }
        }
        cnt[i] = s;
    }
    int local = cnt[0] + cnt[1] + cnt[2] + cnt[3];
    sums[t] = local;
    __syncthreads();
    for (int off = 1; off < TPB; off <<= 1) {
        int add = (t >= off) ? sums[t - off] : 0;
        __syncthreads();
        sums[t] += add;
        __syncthreads();
    }
    int excl = sums[t] - local;
    if (base + 0 < n) offsets[base + 0] = excl;
    if (base + 1 < n) offsets[base + 1] = excl + cnt[0];
    if (base + 2 < n) offsets[base + 2] = excl + cnt[0] + cnt[1];
    if (base + 3 < n) offsets[base + 3] = excl + cnt[0] + cnt[1] + cnt[2];
    if (t == TPB - 1) blocksums[b] = sums[TPB - 1];
}

// scan3 with scan2 inlined + fused addoff.
__global__ void scan3(int* __restrict__ offsets, const int* __restrict__ blocksums,
                      int* __restrict__ sub, int n, int Etot, int nb) {
    __shared__ int s[TPB];
    __shared__ int excl[TPB];
    int t = threadIdx.x;
    int v = (t < nb) ? blocksums[t] : 0;
    s[t] = v;
    __syncthreads();
    for (int off = 1; off < TPB; off <<= 1) {
        int add = (t >= off) ? s[t - off] : 0;
        __syncthreads();
        s[t] += add;
        __syncthreads();
    }
    excl[t] = s[t] - v;   // exclusive scan of blocksums
    __syncthreads();
    int i = blockIdx.x * TPB + t;
    if (i < n) {
        int vv = offsets[i] + excl[i >> 10];
        offsets[i] = vv;
        #pragma unroll
        for (int b = 0; b < 8; b++) sub[b * n + i] += vv;
    }
    if (i == n) offsets[n] = Etot;
}

// scatter WITHOUT atomics, 4 edges per thread:
// pos = sub_abs[(e>>8)&7][d] + rank[e]
__global__ void scatter_kernel(const int* __restrict__ src0, const int* __restrict__ dst0,
                               const int* __restrict__ src1, const int* __restrict__ dst1,
                               const int* __restrict__ sub,
                               const int* __restrict__ rank, unsigned* __restrict__ records,
                               int E0, int Etot, int N) {
    const int gid = blockIdx.x * TPB + threadIdx.x;
    const int S = gridDim.x * TPB;
    #pragma unroll
    for (int k = 0; k < 4; k++) {
        int e = gid + k * S;
        if (e < Etot) {
            int s, d, setbit;
            if (e < E0) { s = src0[e]; d = dst0[e]; setbit = 0; }
            else        { s = src1[e - E0]; d = dst1[e - E0]; setbit = 1; }
            d = min(max(d, 0), N - 1);
            int pos = sub[((e >> 8) & 7) * N + d] + rank[e];
            pos = min(max(pos, 0), Etot - 1);
            records[pos] = (unsigned)s | ((unsigned)setbit << 24);
        }
    }
}

// ---------------------------------------------------------------------------
// MFMA projection, 128 rows/block. q (bf16) + km (fp8 e4m3).
// kmbuf8 LINE-PAIRED layout [node][256] bytes:
//   set s: k at s*128 + [0,64), m at s*128 + 64 + [0,64)   (within h*8+c)
// -> one edge's k-read and m-read land in the SAME 128B L2/HBM line.
// Write side: group permutation only; each ct-tile still writes 16
// consecutive bytes (groups are 64-aligned, tiles 16-wide) -> coalesced.
// ---------------------------------------------------------------------------
__global__ __launch_bounds__(TPB) void proj_mfma(const float* __restrict__ x,
                                                 const unsigned short* __restrict__ Wpack,
                                                 const float* __restrict__ bbig,
                                                 unsigned short* __restrict__ qbuf,
                                                 unsigned char* __restrict__ kmbuf8,
                                                 int N) {
    const int lane = threadIdx.x & 63;
    const int wv = threadIdx.x >> 6;
    const int rb0 = blockIdx.x * 128 + wv * 16;
    const int rb1 = rb0 + 64;
    const int arow0 = min(rb0 + (lane & 15), N - 1);
    const int arow1 = min(rb1 + (lane & 15), N - 1);
    const int kbase = (lane >> 4) * 8;

    bf16x8 afA[2], afB[2];
    #pragma unroll
    for (int kt = 0; kt < 2; kt++) {
        const float* xp = x + (size_t)arow0 * 64 + kt * 32 + kbase;
        float4 v0 = *(const float4*)xp;
        float4 v1 = *(const float4*)(xp + 4);
        bf16x8 a;
        a[0] = (short)f2bf(v0.x); a[1] = (short)f2bf(v0.y);
        a[2] = (short)f2bf(v0.z); a[3] = (short)f2bf(v0.w);
        a[4] = (short)f2bf(v1.x); a[5] = (short)f2bf(v1.y);
        a[6] = (short)f2bf(v1.z); a[7] = (short)f2bf(v1.w);
        afA[kt] = a;
        const float* xq = x + (size_t)arow1 * 64 + kt * 32 + kbase;
        float4 w0 = *(const float4*)xq;
        float4 w1 = *(const float4*)(xq + 4);
        bf16x8 b;
        b[0] = (short)f2bf(w0.x); b[1] = (short)f2bf(w0.y);
        b[2] = (short)f2bf(w0.z); b[3] = (short)f2bf(w0.w);
        b[4] = (short)f2bf(w1.x); b[5] = (short)f2bf(w1.y);
        b[6] = (short)f2bf(w1.z); b[7] = (short)f2bf(w1.w);
        afB[kt] = b;
    }

    const int colq = lane & 15;
    const int rgrp = (lane >> 4) * 4;

    for (int ct = 0; ct < 20; ct++) {
        bf16x8 b0 = *(const bf16x8*)(Wpack + ((size_t)(ct * 2 + 0) * 64 + lane) * 8);
        bf16x8 b1 = *(const bf16x8*)(Wpack + ((size_t)(ct * 2 + 1) * 64 + lane) * 8);
        f32x4 accA = {0.f, 0.f, 0.f, 0.f};
        accA = __builtin_amdgcn_mfma_f32_16x16x32_bf16(afA[0], b0, accA, 0, 0, 0);
        accA = __builtin_amdgcn_mfma_f32_16x16x32_bf16(afA[1], b1, accA, 0, 0, 0);
        f32x4 accB = {0.f, 0.f, 0.f, 0.f};
        accB = __builtin_amdgcn_mfma_f32_16x16x32_bf16(afB[0], b0, accB, 0, 0, 0);
        accB = __builtin_amdgcn_mfma_f32_16x16x32_bf16(afB[1], b1, accB, 0, 0, 0);
        const int col = ct * 16 + colq;
        const float bv = bbig[col];
        if (ct < 4) {
            #pragma unroll
            for (int r = 0; r < 4; r++) {
                int row = rb0 + rgrp + r;
                if (row < N) qbuf[(size_t)row * 64 + col] = f2bf(accA[r] + bv);
                int row2 = rb1 + rgrp + r;
                if (row2 < N) qbuf[(size_t)row2 * 64 + col] = f2bf(accB[r] + bv);
            }
        } else {
            // groups: cm>>6 = 0:k0 1:k1 2:m0 3:m1 -> addr = set*128 + ism*64 + w
            const int cm = col - 64;
            const int g = cm >> 6, w = cm & 63;
            const int addr = (g & 1) * 128 + (g >> 1) * 64 + w;
            #pragma unroll
            for (int r = 0; r < 4; r++) {
                int row = rb0 + rgrp + r;
                if (row < N) kmbuf8[(size_t)row * 256 + addr] = enc8(accA[r] + bv);
                int row2 = rb1 + rgrp + r;
                if (row2 < N) kmbuf8[(size_t)row2 * 256 + addr] = enc8(accB[r] + bv);
            }
        }
    }
}

// ---------------------------------------------------------------------------
// Pool (fp8, line-paired k||m): one 8-lane group per receiver.
// lane = (g, j). Per edge the 8 lanes read k-64B + m-64B from ONE 128B line.
// No online max (scores O(0.1); fminf guards; softmax shift-invariance).
// ---------------------------------------------------------------------------
__global__ __launch_bounds__(TPB) void pool_kernel(const unsigned short* __restrict__ qbuf,
                                                   const unsigned char* __restrict__ kmbuf8,
                                                   const unsigned* __restrict__ records,
                                                   const int* __restrict__ offsets,
                                                   unsigned short* __restrict__ pooledN,
                                                   int N) {
    const int lane = threadIdx.x & 63;
    const int j = lane & 7;
    const int r = ((blockIdx.x * TPB + threadIdx.x) >> 6) * 8 + (lane >> 3);
    if (r >= N) return;
    const int beg = offsets[r], end = offsets[r + 1];

    uint4 qv = *(const uint4*)(qbuf + (size_t)r * 64 + (j << 3));
    float qa0 = loF(qv.x), qa1 = hiF(qv.x), qa2 = loF(qv.y), qa3 = hiF(qv.y);
    float qa4 = loF(qv.z), qa5 = hiF(qv.z), qa6 = loF(qv.w), qa7 = hiF(qv.w);

    float d_run = 0.f;
    float p0 = 0.f, p1 = 0.f, p2 = 0.f, p3 = 0.f, p4 = 0.f, p5 = 0.f, p6 = 0.f, p7 = 0.f;

#define EDGE(T) {                                                              \
        unsigned rec = records[T];                                             \
        size_t base = ((size_t)(rec & 0xFFFFFFu) << 8) + (((rec >> 24) & 1u) << 7) + (j << 3); \
        uint2 kv = *(const uint2*)(kmbuf8 + base);                             \
        uint2 mv = *(const uint2*)(kmbuf8 + base + 64);                        \
        float kf[8], mf[8];                                                    \
        dec8x8(kv, kf); dec8x8(mv, mf);                                        \
        float s = kf[0] * qa0 + kf[1] * qa1 + kf[2] * qa2 + kf[3] * qa3        \
                + kf[4] * qa4 + kf[5] * qa5 + kf[6] * qa6 + kf[7] * qa7;       \
        float c = __expf(fminf(s, 60.f));                                      \
        d_run += c;                                                            \
        p0 += c * mf[0]; p1 += c * mf[1]; p2 += c * mf[2]; p3 += c * mf[3];    \
        p4 += c * mf[4]; p5 += c * mf[5]; p6 += c * mf[6]; p7 += c * mf[7];    \
    }

    int t = beg;
    for (; t + 1 < end; t += 2) { EDGE(t); EDGE(t + 1); }
    if (t < end) EDGE(t);
#undef EDGE

    const float inv = (end > beg) ? 1.f / d_run : 0.f;
    uint4 ov;
    ov.x = (unsigned)f2bf(p0 * inv) | ((unsigned)f2bf(p1 * inv) << 16);
    ov.y = (unsigned)f2bf(p2 * inv) | ((unsigned)f2bf(p3 * inv) << 16);
    ov.z = (unsigned)f2bf(p4 * inv) | ((unsigned)f2bf(p5 * inv) << 16);
    ov.w = (unsigned)f2bf(p6 * inv) | ((unsigned)f2bf(p7 * inv) << 16);
    *(uint4*)(pooledN + (size_t)r * 64 + (j << 3)) = ov;
}

// ---------------------------------------------------------------------------
// MFMA final: out = LN( sc*(gelu(pooledN) @ Wa + ba) + (1-sc)*x ).
// ---------------------------------------------------------------------------
__global__ __launch_bounds__(TPB) void final_mfma(const float* __restrict__ x,
                                                  const unsigned short* __restrict__ pooledN,
                                                  const unsigned short* __restrict__ Wapack,
                                                  const float* __restrict__ ba,
                                                  const float* __restrict__ skipw,
                                                  const float* __restrict__ gamma,
                                                  const float* __restrict__ beta,
                                                  float* __restrict__ out, int N) {
    const int lane = threadIdx.x & 63;
    const int wv = threadIdx.x >> 6;
    const int rowbase = blockIdx.x * 64 + wv * 16;
    const int arow = min(rowbase + (lane & 15), N - 1);
    const int kbase = (lane >> 4) * 8;
    const float sc = 1.f / (1.f + __expf(-skipw[0]));

    bf16x8 afrag[2];
    #pragma unroll
    for (int kt = 0; kt < 2; kt++) {
        uint4 pv = *(const uint4*)(pooledN + (size_t)arow * 64 + kt * 32 + kbase);
        float g[8];
        g[0] = loF(pv.x); g[1] = bf2f((unsigned short)(pv.x >> 16));
        g[2] = loF(pv.y); g[3] = bf2f((unsigned short)(pv.y >> 16));
        g[4] = loF(pv.z); g[5] = bf2f((unsigned short)(pv.z >> 16));
        g[6] = loF(pv.w); g[7] = bf2f((unsigned short)(pv.w >> 16));
        bf16x8 a;
        #pragma unroll
        for (int i = 0; i < 8; i++) {
            float gg = 0.5f * g[i] * (1.f + erff(g[i] * 0.70710678118654752f));
            a[i] = (short)f2bf(gg);
        }
        afrag[kt] = a;
    }

    const int colq = lane & 15;
    const int rgrp = (lane >> 4) * 4;

    float o[4][4];   // [ct][r] post-skip values
    #pragma unroll
    for (int ct = 0; ct < 4; ct++) {
        bf16x8 b0 = *(const bf16x8*)(Wapack + ((size_t)(ct * 2 + 0) * 64 + lane) * 8);
        bf16x8 b1 = *(const bf16x8*)(Wapack + ((size_t)(ct * 2 + 1) * 64 + lane) * 8);
        f32x4 acc = {0.f, 0.f, 0.f, 0.f};
        acc = __builtin_amdgcn_mfma_f32_16x16x32_bf16(afrag[0], b0, acc, 0, 0, 0);
        acc = __builtin_amdgcn_mfma_f32_16x16x32_bf16(afrag[1], b1, acc, 0, 0, 0);
        const int col = ct * 16 + colq;
        const float bav = ba[col];
        #pragma unroll
        for (int r = 0; r < 4; r++) {
            int row = min(rowbase + rgrp + r, N - 1);
            float xv = x[(size_t)row * 64 + col];
            o[ct][r] = sc * (acc[r] + bav) + (1.f - sc) * xv;
        }
    }

    #pragma unroll
    for (int r = 0; r < 4; r++) {
        float s1 = o[0][r] + o[1][r] + o[2][r] + o[3][r];
        float s2 = o[0][r] * o[0][r] + o[1][r] * o[1][r]
                 + o[2][r] * o[2][r] + o[3][r] * o[3][r];
        #pragma unroll
        for (int off = 1; off <= 8; off <<= 1) {
            s1 += __shfl_xor(s1, off, 64);
            s2 += __shfl_xor(s2, off, 64);
        }
        float mu = s1 * (1.f / 64.f);
        float var = s2 * (1.f / 64.f) - mu * mu;
        float rs = rsqrtf(var + 1e-3f);
        const int row = rowbase + rgrp + r;
        if (row < N) {
            #pragma unroll
            for (int ct = 0; ct < 4; ct++) {
                const int col = ct * 16 + colq;
                out[(size_t)row * 64 + col] = gamma[col] * (o[ct][r] - mu) * rs + beta[col];
            }
        }
    }
}

extern "C" void kernel_launch(void* const* d_in, const int* in_sizes, int n_in,
                              void* d_out, int out_size, void* d_ws, size_t ws_size,
                              hipStream_t stream) {
    const float* x      = (const float*)d_in[0];
    const int*   src0   = (const int*)d_in[1];
    const int*   dst0   = (const int*)d_in[2];
    const int*   src1   = (const int*)d_in[3];
    const int*   dst1   = (const int*)d_in[4];
    const float* Wk     = (const float*)d_in[5];
    const float* bk     = (const float*)d_in[6];
    const float* Wm     = (const float*)d_in[7];
    const float* bm     = (const float*)d_in[8];
    const float* Wq     = (const float*)d_in[9];
    const float* bq     = (const float*)d_in[10];
    const float* Wa     = (const float*)d_in[11];
    const float* ba     = (const float*)d_in[12];
    const float* Watt0  = (const float*)d_in[13];
    const float* Wmsg0  = (const float*)d_in[14];
    const float* prior0 = (const float*)d_in[15];
    const float* Watt1  = (const float*)d_in[16];
    const float* Wmsg1  = (const float*)d_in[17];
    const float* prior1 = (const float*)d_in[18];
    const float* skipw  = (const float*)d_in[19];
    const float* gamma  = (const float*)d_in[20];
    const float* beta   = (const float*)d_in[21];

    const int N  = in_sizes[0] / 64;
    const int E0 = in_sizes[1];
    const int E1 = in_sizes[3];
    const int Etot = E0 + E1;

    // workspace layout
    float* ws       = (float*)d_ws;
    float* bbig     = ws;                                   // 320 f32
    unsigned short* Wpack  = (unsigned short*)(bbig + 320); // 40*64*8 bf16 (40 KB)
    unsigned short* Wapack = Wpack + 40 * 64 * 8;           // 8*64*8 bf16 (8 KB)
    unsigned short* qbuf   = Wapack + 8 * 64 * 8;           // N*64 bf16
    unsigned short* pooledN = qbuf + (size_t)N * 64;        // N*64 bf16
    unsigned char* kmbuf8  = (unsigned char*)(pooledN + (size_t)N * 64);  // N*256 fp8
    int* sub        = (int*)(kmbuf8 + (size_t)N * 256);     // 8*N (counts -> abs bases)
    int* offsets    = sub + (size_t)8 * N;                  // N+1
    int* blocksums  = offsets + N + 1;                      // <=256
    int* rank       = blocksums + 512;                      // Etot
    unsigned* records = (unsigned*)(rank + Etot);           // Etot

    const int nb1 = (N + 1023) / 1024;                      // <=98 for N=100K
    const int gE4 = (Etot + 4 * TPB - 1) / (4 * TPB);       // 4 edges per thread

    setup_kernel<<<32, TPB, 0, stream>>>(Wq, bq, Wk, bk, Wm, bm, Watt0, prior0,
                                         Watt1, prior1, Wmsg0, Wmsg1, Wa,
                                         bbig, Wpack, Wapack, (int4*)sub, 2 * N);

    proj_mfma<<<(N + 127) / 128, TPB, 0, stream>>>(x, Wpack, bbig, qbuf, kmbuf8, N);

    hist_kernel<<<gE4, TPB, 0, stream>>>(dst0, dst1, sub, rank, E0, Etot, N);

    scan1<<<nb1, TPB, 0, stream>>>(sub, offsets, blocksums, N);
    scan3<<<(N + 1 + TPB - 1) / TPB, TPB, 0, stream>>>(offsets, blocksums, sub, N, Etot, nb1);

    scatter_kernel<<<gE4, TPB, 0, stream>>>(src0, dst0, src1, dst1, sub,
                                            rank, records, E0, Etot, N);

    pool_kernel<<<((size_t)N * 8 + TPB - 1) / TPB, TPB, 0, stream>>>(qbuf, kmbuf8, records,
                                                                     offsets, pooledN, N);

    final_mfma<<<(N + 63) / 64, TPB, 0, stream>>>(x, pooledN, Wapack, ba, skipw,
                                                  gamma, beta, (float*)d_out, N);
}

// Round 19
// 145.866 us; speedup vs baseline: 1.1306x; 1.0476x over previous
//
#include <hip/hip_runtime.h>
#include <hip/hip_fp16.h>
#include <cstdint>
#include <cstddef>

#define TPB 256
static constexpr float RSQRT_C_F = 0.35355339059327373f;  // 1/sqrt(8)

typedef __attribute__((ext_vector_type(8))) short bf16x8;
typedef __attribute__((ext_vector_type(4))) float f32x4;
typedef __attribute__((ext_vector_type(2))) float f32x2;

#if __has_builtin(__builtin_amdgcn_cvt_pk_f32_fp8) && __has_builtin(__builtin_amdgcn_cvt_pk_fp8_f32)
#define USE_HW_FP8 1
#endif

__device__ __forceinline__ unsigned short f2bf(float f) {
    unsigned u = __float_as_uint(f);
    u += 0x7FFFu + ((u >> 16) & 1u);          // round-to-nearest-even
    return (unsigned short)(u >> 16);
}
__device__ __forceinline__ float bf2f(unsigned short h) {
    return __uint_as_float((unsigned)h << 16);
}
__device__ __forceinline__ float loF(unsigned u) { return __uint_as_float(u << 16); }
__device__ __forceinline__ float hiF(unsigned u) { return __uint_as_float(u); }

// ---- fp8 e4m3 encode/decode (HW path via v_cvt_*, SW fallback) ----
__device__ __forceinline__ unsigned char enc8(float v) {
#ifdef USE_HW_FP8
    return (unsigned char)(__builtin_amdgcn_cvt_pk_fp8_f32(v, v, 0, false) & 0xff);
#else
    unsigned s = (__float_as_uint(v) >> 24) & 0x80u;
    float a = fabsf(v);
    if (a < 0.015625f) {                        // subnormal region (< 2^-6)
        int m = __float2int_rn(a * 512.f);      // 0..8
        return (unsigned char)(s | (unsigned)m);
    }
    if (a > 448.f) return (unsigned char)(s | 0x7e);
    unsigned u = __float_as_uint(a);
    u += 0x7FFFFu + ((u >> 20) & 1u);           // RNE into bit 20
    unsigned e8 = ((u >> 23) & 0xffu) - 120u;
    unsigned m3 = (u >> 20) & 7u;
    if (e8 > 15u) return (unsigned char)(s | 0x7e);
    return (unsigned char)(s | (e8 << 3) | m3);
#endif
}

__device__ __forceinline__ void dec8x8(uint2 v, float* o) {
#ifdef USE_HW_FP8
    f32x2 a = __builtin_amdgcn_cvt_pk_f32_fp8((int)v.x, false);
    f32x2 b = __builtin_amdgcn_cvt_pk_f32_fp8((int)v.x, true);
    f32x2 c = __builtin_amdgcn_cvt_pk_f32_fp8((int)v.y, false);
    f32x2 d = __builtin_amdgcn_cvt_pk_f32_fp8((int)v.y, true);
    o[0] = a.x; o[1] = a.y; o[2] = b.x; o[3] = b.y;
    o[4] = c.x; o[5] = c.y; o[6] = d.x; o[7] = d.y;
#else
    unsigned w[2] = {v.x, v.y};
    #pragma unroll
    for (int i = 0; i < 8; i++) {
        unsigned bb = (w[i >> 2] >> ((i & 3) * 8)) & 0xffu;
        unsigned short hs = (unsigned short)(((bb & 0x80u) << 8) | ((bb & 0x7fu) << 7));
        __half h = *reinterpret_cast<__half*>(&hs);   // e4m3 bits in f16 slot => val/256
        o[i] = 256.f * __half2float(h);
    }
#endif
}

// Wbig element (i = input row 0..63, col = fused output col 0..319), on the fly
__device__ __forceinline__ float wbig_elem(const float* __restrict__ Wq,
                                           const float* __restrict__ Wk,
                                           const float* __restrict__ Wm,
                                           const float* __restrict__ Watt0,
                                           const float* __restrict__ Watt1,
                                           const float* __restrict__ Wmsg0,
                                           const float* __restrict__ Wmsg1,
                                           const float* __restrict__ prior0,
                                           const float* __restrict__ prior1,
                                           int i, int col) {
    if (col < 64) return Wq[i * 64 + col];
    int j = col - 64, set = j >> 6, l = j & 63, h = l >> 3, lc = l & 7;
    const float* Win = (set < 2) ? Wk : Wm;
    const float* T = (set == 0) ? Watt0 : (set == 1) ? Watt1 : (set == 2) ? Wmsg0 : Wmsg1;
    float scale = (set == 0) ? prior0[h] * RSQRT_C_F
                : (set == 1) ? prior1[h] * RSQRT_C_F : 1.f;
    float acc = 0.f;
    #pragma unroll
    for (int c = 0; c < 8; c++) acc += Win[i * 64 + h * 8 + c] * T[h * 64 + c * 8 + lc];
    return acc * scale;
}

// ---------------------------------------------------------------------------
// setup_kernel (32 blocks): blocks 0-11 pack Wpack/Wapack (direct-compute);
// blocks 12-13 build bbig[320]; blocks 14-31 zero sub.
// ---------------------------------------------------------------------------
__global__ void setup_kernel(const float* __restrict__ Wq, const float* __restrict__ bq,
                             const float* __restrict__ Wk, const float* __restrict__ bk,
                             const float* __restrict__ Wm, const float* __restrict__ bm,
                             const float* __restrict__ Watt0, const float* __restrict__ prior0,
                             const float* __restrict__ Watt1, const float* __restrict__ prior1,
                             const float* __restrict__ Wmsg0, const float* __restrict__ Wmsg1,
                             const float* __restrict__ Wa,
                             float* __restrict__ bbig,
                             unsigned short* __restrict__ Wpack,
                             unsigned short* __restrict__ Wapack,
                             int4* __restrict__ subzero, int n4) {
    const int b = blockIdx.x, t = threadIdx.x;
    if (b < 12) {
        int p = b * TPB + t;
        if (p >= 48 * 64) return;
        bool isWa = (p >= 40 * 64);
        int pl = isWa ? p - 40 * 64 : p;
        int lane = pl & 63, ctkt = pl >> 6;
        int ct = ctkt >> 1, kt = ctkt & 1;
        int kbase = kt * 32 + (lane >> 4) * 8;
        int col = ct * 16 + (lane & 15);
        unsigned short h[8];
        if (isWa) {
            #pragma unroll
            for (int j = 0; j < 8; j++) h[j] = f2bf(Wa[(size_t)(kbase + j) * 64 + col]);
        } else {
            #pragma unroll
            for (int j = 0; j < 8; j++)
                h[j] = f2bf(wbig_elem(Wq, Wk, Wm, Watt0, Watt1, Wmsg0, Wmsg1,
                                      prior0, prior1, kbase + j, col));
        }
        uint4 pk;
        pk.x = (unsigned)h[0] | ((unsigned)h[1] << 16);
        pk.y = (unsigned)h[2] | ((unsigned)h[3] << 16);
        pk.z = (unsigned)h[4] | ((unsigned)h[5] << 16);
        pk.w = (unsigned)h[6] | ((unsigned)h[7] << 16);
        unsigned short* dst = isWa ? Wapack : Wpack;
        *(uint4*)&dst[(size_t)pl * 8] = pk;
    } else if (b < 14) {
        int col = (b - 12) * TPB + t;
        if (col >= 320) return;
        float v;
        if (col < 64) {
            v = bq[col];
        } else {
            int j = col - 64, set = j >> 6, l = j & 63, h = l >> 3, lc = l & 7;
            const float* bin = (set < 2) ? bk : bm;
            const float* T = (set == 0) ? Watt0 : (set == 1) ? Watt1 : (set == 2) ? Wmsg0 : Wmsg1;
            float scale = (set == 0) ? prior0[h] * RSQRT_C_F
                        : (set == 1) ? prior1[h] * RSQRT_C_F : 1.f;
            float acc = 0.f;
            #pragma unroll
            for (int c = 0; c < 8; c++) acc += bin[h * 8 + c] * T[h * 64 + c * 8 + lc];
            v = acc * scale;
        }
        bbig[col] = v;
    } else {
        int i = (b - 14) * TPB + t;
        int stride = 18 * TPB;
        for (; i < n4; i += stride) subzero[i] = int4{0, 0, 0, 0};
    }
}

// ---------------------------------------------------------------------------
// hist, 4 independent edges per thread. Bucket = (e>>8)&7 matches scatter.
// ---------------------------------------------------------------------------
__global__ void hist_kernel(const int* __restrict__ dst0, const int* __restrict__ dst1,
                            int* __restrict__ sub, int* __restrict__ rank,
                            int E0, int Etot, int N) {
    const int gid = blockIdx.x * TPB + threadIdx.x;
    const int S = gridDim.x * TPB;
    #pragma unroll
    for (int k = 0; k < 4; k++) {
        int e = gid + k * S;
        if (e < Etot) {
            int d = (e < E0) ? dst0[e] : dst1[e - E0];
            d = min(max(d, 0), N - 1);
            rank[e] = atomicAdd(&sub[((e >> 8) & 7) * N + d], 1);
        }
    }
}

// ---- scan1 (sumsub fused): reads sub counts, writes exclusive bases + offsets ----
__global__ void scan1(int* __restrict__ sub, int* __restrict__ offsets,
                      int* __restrict__ blocksums, int n) {
    __shared__ int sums[TPB];
    int b = blockIdx.x, t = threadIdx.x;
    int base = b * 1024 + t * 4;
    int cnt[4];
    #pragma unroll
    for (int i = 0; i < 4; i++) {
        int d = base + i;
        int s = 0;
        if (d < n) {
            #pragma unroll
            for (int bb = 0; bb < 8; bb++) {
                int v = sub[bb * n + d];
                sub[bb * n + d] = s;     // exclusive prefix base
                s += v;
            }
        }
        cnt[i] = s;
    }
    int local = cnt[0] + cnt[1] + cnt[2] + cnt[3];
    sums[t] = local;
    __syncthreads();
    for (int off = 1; off < TPB; off <<= 1) {
        int add = (t >= off) ? sums[t - off] : 0;
        __syncthreads();
        sums[t] += add;
        __syncthreads();
    }
    int excl = sums[t] - local;
    if (base + 0 < n) offsets[base + 0] = excl;
    if (base + 1 < n) offsets[base + 1] = excl + cnt[0];
    if (base + 2 < n) offsets[base + 2] = excl + cnt[0] + cnt[1];
    if (base + 3 < n) offsets[base + 3] = excl + cnt[0] + cnt[1] + cnt[2];
    if (t == TPB - 1) blocksums[b] = sums[TPB - 1];
}

// scan3 with scan2 inlined + fused addoff.
__global__ void scan3(int* __restrict__ offsets, const int* __restrict__ blocksums,
                      int* __restrict__ sub, int n, int Etot, int nb) {
    __shared__ int s[TPB];
    __shared__ int excl[TPB];
    int t = threadIdx.x;
    int v = (t < nb) ? blocksums[t] : 0;
    s[t] = v;
    __syncthreads();
    for (int off = 1; off < TPB; off <<= 1) {
        int add = (t >= off) ? s[t - off] : 0;
        __syncthreads();
        s[t] += add;
        __syncthreads();
    }
    excl[t] = s[t] - v;   // exclusive scan of blocksums
    __syncthreads();
    int i = blockIdx.x * TPB + t;
    if (i < n) {
        int vv = offsets[i] + excl[i >> 10];
        offsets[i] = vv;
        #pragma unroll
        for (int b = 0; b < 8; b++) sub[b * n + i] += vv;
    }
    if (i == n) offsets[n] = Etot;
}

// scatter WITHOUT atomics, 4 edges per thread:
// pos = sub_abs[(e>>8)&7][d] + rank[e]
__global__ void scatter_kernel(const int* __restrict__ src0, const int* __restrict__ dst0,
                               const int* __restrict__ src1, const int* __restrict__ dst1,
                               const int* __restrict__ sub,
                               const int* __restrict__ rank, unsigned* __restrict__ records,
                               int E0, int Etot, int N) {
    const int gid = blockIdx.x * TPB + threadIdx.x;
    const int S = gridDim.x * TPB;
    #pragma unroll
    for (int k = 0; k < 4; k++) {
        int e = gid + k * S;
        if (e < Etot) {
            int s, d, setbit;
            if (e < E0) { s = src0[e]; d = dst0[e]; setbit = 0; }
            else        { s = src1[e - E0]; d = dst1[e - E0]; setbit = 1; }
            d = min(max(d, 0), N - 1);
            int pos = sub[((e >> 8) & 7) * N + d] + rank[e];
            pos = min(max(pos, 0), Etot - 1);
            records[pos] = (unsigned)s | ((unsigned)setbit << 24);
        }
    }
}

// ---------------------------------------------------------------------------
// MFMA projection, 128 rows/block, LDS-staged wide-store epilogue.
// Per wave: 2 stripes x 16 rows; 5 groups of 4 ct-tiles. Each group's outputs
// staged in a 4KB/wave LDS tile (narrow ds_write), then read back wide and
// stored as fully-coalesced dwordx4 (12 wide global stores vs 160 narrow).
// kmbuf8 LINE-PAIRED layout (R18-proven): set s: k at s*128, m at s*128+64.
// ---------------------------------------------------------------------------
__global__ __launch_bounds__(TPB) void proj_mfma(const float* __restrict__ x,
                                                 const unsigned short* __restrict__ Wpack,
                                                 const float* __restrict__ bbig,
                                                 unsigned short* __restrict__ qbuf,
                                                 unsigned char* __restrict__ kmbuf8,
                                                 int N) {
    __shared__ unsigned char ldsb[4][4096];
    const int lane = threadIdx.x & 63;
    const int wv = threadIdx.x >> 6;
    unsigned char* L = ldsb[wv];
    const int rb0 = blockIdx.x * 128 + wv * 16;
    const int rb1 = rb0 + 64;
    const int arow0 = min(rb0 + (lane & 15), N - 1);
    const int arow1 = min(rb1 + (lane & 15), N - 1);
    const int kbase = (lane >> 4) * 8;

    bf16x8 afA[2], afB[2];
    #pragma unroll
    for (int kt = 0; kt < 2; kt++) {
        const float* xp = x + (size_t)arow0 * 64 + kt * 32 + kbase;
        float4 v0 = *(const float4*)xp;
        float4 v1 = *(const float4*)(xp + 4);
        bf16x8 a;
        a[0] = (short)f2bf(v0.x); a[1] = (short)f2bf(v0.y);
        a[2] = (short)f2bf(v0.z); a[3] = (short)f2bf(v0.w);
        a[4] = (short)f2bf(v1.x); a[5] = (short)f2bf(v1.y);
        a[6] = (short)f2bf(v1.z); a[7] = (short)f2bf(v1.w);
        afA[kt] = a;
        const float* xq = x + (size_t)arow1 * 64 + kt * 32 + kbase;
        float4 w0 = *(const float4*)xq;
        float4 w1 = *(const float4*)(xq + 4);
        bf16x8 b;
        b[0] = (short)f2bf(w0.x); b[1] = (short)f2bf(w0.y);
        b[2] = (short)f2bf(w0.z); b[3] = (short)f2bf(w0.w);
        b[4] = (short)f2bf(w1.x); b[5] = (short)f2bf(w1.y);
        b[6] = (short)f2bf(w1.z); b[7] = (short)f2bf(w1.w);
        afB[kt] = b;
    }

    const int colq = lane & 15;
    const int rgrp = (lane >> 4) * 4;
    const int rrow = lane >> 2;      // readback row 0..15
    const int rqt = lane & 3;        // readback quarter 0..3

    for (int g = 0; g < 5; g++) {
        #pragma unroll
        for (int ct4 = 0; ct4 < 4; ct4++) {
            const int ct = g * 4 + ct4;
            bf16x8 b0 = *(const bf16x8*)(Wpack + ((size_t)(ct * 2 + 0) * 64 + lane) * 8);
            bf16x8 b1 = *(const bf16x8*)(Wpack + ((size_t)(ct * 2 + 1) * 64 + lane) * 8);
            f32x4 accA = {0.f, 0.f, 0.f, 0.f};
            accA = __builtin_amdgcn_mfma_f32_16x16x32_bf16(afA[0], b0, accA, 0, 0, 0);
            accA = __builtin_amdgcn_mfma_f32_16x16x32_bf16(afA[1], b1, accA, 0, 0, 0);
            f32x4 accB = {0.f, 0.f, 0.f, 0.f};
            accB = __builtin_amdgcn_mfma_f32_16x16x32_bf16(afB[0], b0, accB, 0, 0, 0);
            accB = __builtin_amdgcn_mfma_f32_16x16x32_bf16(afB[1], b1, accB, 0, 0, 0);
            const float bv = bbig[ct * 16 + colq];
            const int cig = ct4 * 16 + colq;   // col within group (0..63)
            if (g == 0) {
                #pragma unroll
                for (int r = 0; r < 4; r++) {
                    *(unsigned short*)&L[(rgrp + r) * 128 + cig * 2]        = f2bf(accA[r] + bv);
                    *(unsigned short*)&L[2048 + (rgrp + r) * 128 + cig * 2] = f2bf(accB[r] + bv);
                }
            } else {
                #pragma unroll
                for (int r = 0; r < 4; r++) {
                    L[(rgrp + r) * 64 + cig]        = enc8(accA[r] + bv);
                    L[1024 + (rgrp + r) * 64 + cig] = enc8(accB[r] + bv);
                }
            }
        }
        __syncthreads();
        if (g == 0) {
            #pragma unroll
            for (int s = 0; s < 2; s++) {
                int row = (s ? rb1 : rb0) + rrow;
                if (row < N) {
                    uint4 v0 = *(const uint4*)&L[s * 2048 + rrow * 128 + rqt * 32];
                    uint4 v1 = *(const uint4*)&L[s * 2048 + rrow * 128 + rqt * 32 + 16];
                    unsigned char* dst = (unsigned char*)qbuf + (size_t)row * 128 + rqt * 32;
                    *(uint4*)dst = v0;
                    *(uint4*)(dst + 16) = v1;
                }
            }
        } else {
            const int gg = g - 1;                              // 0:k0 1:k1 2:m0 3:m1
            const int gbase = (gg & 1) * 128 + (gg >> 1) * 64; // line-paired plane base
            #pragma unroll
            for (int s = 0; s < 2; s++) {
                int row = (s ? rb1 : rb0) + rrow;
                if (row < N) {
                    uint4 v = *(const uint4*)&L[s * 1024 + rrow * 64 + rqt * 16];
                    *(uint4*)(kmbuf8 + (size_t)row * 256 + gbase + rqt * 16) = v;
                }
            }
        }
        __syncthreads();
    }
}

// ---------------------------------------------------------------------------
// Pool (fp8, line-paired k||m): one 8-lane group per receiver.
// lane = (g, j). Per edge the 8 lanes read k-64B + m-64B from ONE 128B line.
// No online max (scores O(0.1); fminf guards; softmax shift-invariance).
// ---------------------------------------------------------------------------
__global__ __launch_bounds__(TPB) void pool_kernel(const unsigned short* __restrict__ qbuf,
                                                   const unsigned char* __restrict__ kmbuf8,
                                                   const unsigned* __restrict__ records,
                                                   const int* __restrict__ offsets,
                                                   unsigned short* __restrict__ pooledN,
                                                   int N) {
    const int lane = threadIdx.x & 63;
    const int j = lane & 7;
    const int r = ((blockIdx.x * TPB + threadIdx.x) >> 6) * 8 + (lane >> 3);
    if (r >= N) return;
    const int beg = offsets[r], end = offsets[r + 1];

    uint4 qv = *(const uint4*)(qbuf + (size_t)r * 64 + (j << 3));
    float qa0 = loF(qv.x), qa1 = hiF(qv.x), qa2 = loF(qv.y), qa3 = hiF(qv.y);
    float qa4 = loF(qv.z), qa5 = hiF(qv.z), qa6 = loF(qv.w), qa7 = hiF(qv.w);

    float d_run = 0.f;
    float p0 = 0.f, p1 = 0.f, p2 = 0.f, p3 = 0.f, p4 = 0.f, p5 = 0.f, p6 = 0.f, p7 = 0.f;

#define EDGE(T) {                                                              \
        unsigned rec = records[T];                                             \
        size_t base = ((size_t)(rec & 0xFFFFFFu) << 8) + (((rec >> 24) & 1u) << 7) + (j << 3); \
        uint2 kv = *(const uint2*)(kmbuf8 + base);                             \
        uint2 mv = *(const uint2*)(kmbuf8 + base + 64);                        \
        float kf[8], mf[8];                                                    \
        dec8x8(kv, kf); dec8x8(mv, mf);                                        \
        float s = kf[0] * qa0 + kf[1] * qa1 + kf[2] * qa2 + kf[3] * qa3        \
                + kf[4] * qa4 + kf[5] * qa5 + kf[6] * qa6 + kf[7] * qa7;       \
        float c = __expf(fminf(s, 60.f));                                      \
        d_run += c;                                                            \
        p0 += c * mf[0]; p1 += c * mf[1]; p2 += c * mf[2]; p3 += c * mf[3];    \
        p4 += c * mf[4]; p5 += c * mf[5]; p6 += c * mf[6]; p7 += c * mf[7];    \
    }

    int t = beg;
    for (; t + 1 < end; t += 2) { EDGE(t); EDGE(t + 1); }
    if (t < end) EDGE(t);
#undef EDGE

    const float inv = (end > beg) ? 1.f / d_run : 0.f;
    uint4 ov;
    ov.x = (unsigned)f2bf(p0 * inv) | ((unsigned)f2bf(p1 * inv) << 16);
    ov.y = (unsigned)f2bf(p2 * inv) | ((unsigned)f2bf(p3 * inv) << 16);
    ov.z = (unsigned)f2bf(p4 * inv) | ((unsigned)f2bf(p5 * inv) << 16);
    ov.w = (unsigned)f2bf(p6 * inv) | ((unsigned)f2bf(p7 * inv) << 16);
    *(uint4*)(pooledN + (size_t)r * 64 + (j << 3)) = ov;
}

// ---------------------------------------------------------------------------
// MFMA final, 128 rows/block (2 stripes share B fragments):
// out = LN( sc*(gelu(pooledN) @ Wa + ba) + (1-sc)*x ).
// ---------------------------------------------------------------------------
__global__ __launch_bounds__(TPB) void final_mfma(const float* __restrict__ x,
                                                  const unsigned short* __restrict__ pooledN,
                                                  const unsigned short* __restrict__ Wapack,
                                                  const float* __restrict__ ba,
                                                  const float* __restrict__ skipw,
                                                  const float* __restrict__ gamma,
                                                  const float* __restrict__ beta,
                                                  float* __restrict__ out, int N) {
    const int lane = threadIdx.x & 63;
    const int wv = threadIdx.x >> 6;
    const int rb0 = blockIdx.x * 128 + wv * 16;
    const int rb1 = rb0 + 64;
    const int arow0 = min(rb0 + (lane & 15), N - 1);
    const int arow1 = min(rb1 + (lane & 15), N - 1);
    const int kbase = (lane >> 4) * 8;
    const float sc = 1.f / (1.f + __expf(-skipw[0]));

    bf16x8 afA[2], afB[2];
    #pragma unroll
    for (int kt = 0; kt < 2; kt++) {
        #pragma unroll
        for (int s = 0; s < 2; s++) {
            const int arow = s ? arow1 : arow0;
            uint4 pv = *(const uint4*)(pooledN + (size_t)arow * 64 + kt * 32 + kbase);
            float g[8];
            g[0] = loF(pv.x); g[1] = bf2f((unsigned short)(pv.x >> 16));
            g[2] = loF(pv.y); g[3] = bf2f((unsigned short)(pv.y >> 16));
            g[4] = loF(pv.z); g[5] = bf2f((unsigned short)(pv.z >> 16));
            g[6] = loF(pv.w); g[7] = bf2f((unsigned short)(pv.w >> 16));
            bf16x8 a;
            #pragma unroll
            for (int i = 0; i < 8; i++) {
                float gg = 0.5f * g[i] * (1.f + erff(g[i] * 0.70710678118654752f));
                a[i] = (short)f2bf(gg);
            }
            if (s) afB[kt] = a; else afA[kt] = a;
        }
    }

    const int colq = lane & 15;
    const int rgrp = (lane >> 4) * 4;

    float oA[4][4], oB[4][4];   // [ct][r] post-skip values per stripe
    #pragma unroll
    for (int ct = 0; ct < 4; ct++) {
        bf16x8 b0 = *(const bf16x8*)(Wapack + ((size_t)(ct * 2 + 0) * 64 + lane) * 8);
        bf16x8 b1 = *(const bf16x8*)(Wapack + ((size_t)(ct * 2 + 1) * 64 + lane) * 8);
        f32x4 accA = {0.f, 0.f, 0.f, 0.f};
        accA = __builtin_amdgcn_mfma_f32_16x16x32_bf16(afA[0], b0, accA, 0, 0, 0);
        accA = __builtin_amdgcn_mfma_f32_16x16x32_bf16(afA[1], b1, accA, 0, 0, 0);
        f32x4 accB = {0.f, 0.f, 0.f, 0.f};
        accB = __builtin_amdgcn_mfma_f32_16x16x32_bf16(afB[0], b0, accB, 0, 0, 0);
        accB = __builtin_amdgcn_mfma_f32_16x16x32_bf16(afB[1], b1, accB, 0, 0, 0);
        const int col = ct * 16 + colq;
        const float bav = ba[col];
        #pragma unroll
        for (int r = 0; r < 4; r++) {
            int rowA = min(rb0 + rgrp + r, N - 1);
            float xvA = x[(size_t)rowA * 64 + col];
            oA[ct][r] = sc * (accA[r] + bav) + (1.f - sc) * xvA;
            int rowB = min(rb1 + rgrp + r, N - 1);
            float xvB = x[(size_t)rowB * 64 + col];
            oB[ct][r] = sc * (accB[r] + bav) + (1.f - sc) * xvB;
        }
    }

    #pragma unroll
    for (int s = 0; s < 2; s++) {
        float (*o)[4] = s ? oB : oA;
        const int rowbase = s ? rb1 : rb0;
        #pragma unroll
        for (int r = 0; r < 4; r++) {
            float s1 = o[0][r] + o[1][r] + o[2][r] + o[3][r];
            float s2 = o[0][r] * o[0][r] + o[1][r] * o[1][r]
                     + o[2][r] * o[2][r] + o[3][r] * o[3][r];
            #pragma unroll
            for (int off = 1; off <= 8; off <<= 1) {
                s1 += __shfl_xor(s1, off, 64);
                s2 += __shfl_xor(s2, off, 64);
            }
            float mu = s1 * (1.f / 64.f);
            float var = s2 * (1.f / 64.f) - mu * mu;
            float rs = rsqrtf(var + 1e-3f);
            const int row = rowbase + rgrp + r;
            if (row < N) {
                #pragma unroll
                for (int ct = 0; ct < 4; ct++) {
                    const int col = ct * 16 + colq;
                    out[(size_t)row * 64 + col] = gamma[col] * (o[ct][r] - mu) * rs + beta[col];
                }
            }
        }
    }
}

extern "C" void kernel_launch(void* const* d_in, const int* in_sizes, int n_in,
                              void* d_out, int out_size, void* d_ws, size_t ws_size,
                              hipStream_t stream) {
    const float* x      = (const float*)d_in[0];
    const int*   src0   = (const int*)d_in[1];
    const int*   dst0   = (const int*)d_in[2];
    const int*   src1   = (const int*)d_in[3];
    const int*   dst1   = (const int*)d_in[4];
    const float* Wk     = (const float*)d_in[5];
    const float* bk     = (const float*)d_in[6];
    const float* Wm     = (const float*)d_in[7];
    const float* bm     = (const float*)d_in[8];
    const float* Wq     = (const float*)d_in[9];
    const float* bq     = (const float*)d_in[10];
    const float* Wa     = (const float*)d_in[11];
    const float* ba     = (const float*)d_in[12];
    const float* Watt0  = (const float*)d_in[13];
    const float* Wmsg0  = (const float*)d_in[14];
    const float* prior0 = (const float*)d_in[15];
    const float* Watt1  = (const float*)d_in[16];
    const float* Wmsg1  = (const float*)d_in[17];
    const float* prior1 = (const float*)d_in[18];
    const float* skipw  = (const float*)d_in[19];
    const float* gamma  = (const float*)d_in[20];
    const float* beta   = (const float*)d_in[21];

    const int N  = in_sizes[0] / 64;
    const int E0 = in_sizes[1];
    const int E1 = in_sizes[3];
    const int Etot = E0 + E1;

    // workspace layout
    float* ws       = (float*)d_ws;
    float* bbig     = ws;                                   // 320 f32
    unsigned short* Wpack  = (unsigned short*)(bbig + 320); // 40*64*8 bf16 (40 KB)
    unsigned short* Wapack = Wpack + 40 * 64 * 8;           // 8*64*8 bf16 (8 KB)
    unsigned short* qbuf   = Wapack + 8 * 64 * 8;           // N*64 bf16
    unsigned short* pooledN = qbuf + (size_t)N * 64;        // N*64 bf16
    unsigned char* kmbuf8  = (unsigned char*)(pooledN + (size_t)N * 64);  // N*256 fp8
    int* sub        = (int*)(kmbuf8 + (size_t)N * 256);     // 8*N (counts -> abs bases)
    int* offsets    = sub + (size_t)8 * N;                  // N+1
    int* blocksums  = offsets + N + 1;                      // <=256
    int* rank       = blocksums + 512;                      // Etot
    unsigned* records = (unsigned*)(rank + Etot);           // Etot

    const int nb1 = (N + 1023) / 1024;                      // <=98 for N=100K
    const int gE4 = (Etot + 4 * TPB - 1) / (4 * TPB);       // 4 edges per thread

    setup_kernel<<<32, TPB, 0, stream>>>(Wq, bq, Wk, bk, Wm, bm, Watt0, prior0,
                                         Watt1, prior1, Wmsg0, Wmsg1, Wa,
                                         bbig, Wpack, Wapack, (int4*)sub, 2 * N);

    proj_mfma<<<(N + 127) / 128, TPB, 0, stream>>>(x, Wpack, bbig, qbuf, kmbuf8, N);

    hist_kernel<<<gE4, TPB, 0, stream>>>(dst0, dst1, sub, rank, E0, Etot, N);

    scan1<<<nb1, TPB, 0, stream>>>(sub, offsets, blocksums, N);
    scan3<<<(N + 1 + TPB - 1) / TPB, TPB, 0, stream>>>(offsets, blocksums, sub, N, Etot, nb1);

    scatter_kernel<<<gE4, TPB, 0, stream>>>(src0, dst0, src1, dst1, sub,
                                            rank, records, E0, Etot, N);

    pool_kernel<<<((size_t)N * 8 + TPB - 1) / TPB, TPB, 0, stream>>>(qbuf, kmbuf8, records,
                                                                     offsets, pooledN, N);

    final_mfma<<<(N + 127) / 128, TPB, 0, stream>>>(x, pooledN, Wapack, ba, skipw,
                                                    gamma, beta, (float*)d_out, N);
}

// Round 20
// 139.143 us; speedup vs baseline: 1.1853x; 1.0483x over previous
//
#include <hip/hip_runtime.h>
#include <hip/hip_fp16.h>
#include <cstdint>
#include <cstddef>

#define TPB 256
static constexpr float RSQRT_C_F = 0.35355339059327373f;  // 1/sqrt(8)

typedef __attribute__((ext_vector_type(8))) short bf16x8;
typedef __attribute__((ext_vector_type(4))) float f32x4;
typedef __attribute__((ext_vector_type(2))) float f32x2;

#if __has_builtin(__builtin_amdgcn_cvt_pk_f32_fp8) && __has_builtin(__builtin_amdgcn_cvt_pk_fp8_f32)
#define USE_HW_FP8 1
#endif

__device__ __forceinline__ unsigned short f2bf(float f) {
    unsigned u = __float_as_uint(f);
    u += 0x7FFFu + ((u >> 16) & 1u);          // round-to-nearest-even
    return (unsigned short)(u >> 16);
}
__device__ __forceinline__ float bf2f(unsigned short h) {
    return __uint_as_float((unsigned)h << 16);
}
__device__ __forceinline__ float loF(unsigned u) { return __uint_as_float(u << 16); }
__device__ __forceinline__ float hiF(unsigned u) { return __uint_as_float(u); }

// ---- fp8 e4m3 encode/decode (HW path via v_cvt_*, SW fallback) ----
__device__ __forceinline__ unsigned char enc8(float v) {
#ifdef USE_HW_FP8
    return (unsigned char)(__builtin_amdgcn_cvt_pk_fp8_f32(v, v, 0, false) & 0xff);
#else
    unsigned s = (__float_as_uint(v) >> 24) & 0x80u;
    float a = fabsf(v);
    if (a < 0.015625f) {                        // subnormal region (< 2^-6)
        int m = __float2int_rn(a * 512.f);      // 0..8
        return (unsigned char)(s | (unsigned)m);
    }
    if (a > 448.f) return (unsigned char)(s | 0x7e);
    unsigned u = __float_as_uint(a);
    u += 0x7FFFFu + ((u >> 20) & 1u);           // RNE into bit 20
    unsigned e8 = ((u >> 23) & 0xffu) - 120u;
    unsigned m3 = (u >> 20) & 7u;
    if (e8 > 15u) return (unsigned char)(s | 0x7e);
    return (unsigned char)(s | (e8 << 3) | m3);
#endif
}

__device__ __forceinline__ void dec8x8(uint2 v, float* o) {
#ifdef USE_HW_FP8
    f32x2 a = __builtin_amdgcn_cvt_pk_f32_fp8((int)v.x, false);
    f32x2 b = __builtin_amdgcn_cvt_pk_f32_fp8((int)v.x, true);
    f32x2 c = __builtin_amdgcn_cvt_pk_f32_fp8((int)v.y, false);
    f32x2 d = __builtin_amdgcn_cvt_pk_f32_fp8((int)v.y, true);
    o[0] = a.x; o[1] = a.y; o[2] = b.x; o[3] = b.y;
    o[4] = c.x; o[5] = c.y; o[6] = d.x; o[7] = d.y;
#else
    unsigned w[2] = {v.x, v.y};
    #pragma unroll
    for (int i = 0; i < 8; i++) {
        unsigned bb = (w[i >> 2] >> ((i & 3) * 8)) & 0xffu;
        unsigned short hs = (unsigned short)(((bb & 0x80u) << 8) | ((bb & 0x7fu) << 7));
        __half h = *reinterpret_cast<__half*>(&hs);   // e4m3 bits in f16 slot => val/256
        o[i] = 256.f * __half2float(h);
    }
#endif
}

// Wbig element (i = input row 0..63, col = fused output col 0..319), on the fly
__device__ __forceinline__ float wbig_elem(const float* __restrict__ Wq,
                                           const float* __restrict__ Wk,
                                           const float* __restrict__ Wm,
                                           const float* __restrict__ Watt0,
                                           const float* __restrict__ Watt1,
                                           const float* __restrict__ Wmsg0,
                                           const float* __restrict__ Wmsg1,
                                           const float* __restrict__ prior0,
                                           const float* __restrict__ prior1,
                                           int i, int col) {
    if (col < 64) return Wq[i * 64 + col];
    int j = col - 64, set = j >> 6, l = j & 63, h = l >> 3, lc = l & 7;
    const float* Win = (set < 2) ? Wk : Wm;
    const float* T = (set == 0) ? Watt0 : (set == 1) ? Watt1 : (set == 2) ? Wmsg0 : Wmsg1;
    float scale = (set == 0) ? prior0[h] * RSQRT_C_F
                : (set == 1) ? prior1[h] * RSQRT_C_F : 1.f;
    float acc = 0.f;
    #pragma unroll
    for (int c = 0; c < 8; c++) acc += Win[i * 64 + h * 8 + c] * T[h * 64 + c * 8 + lc];
    return acc * scale;
}

// ---------------------------------------------------------------------------
// setup_kernel (32 blocks): blocks 0-11 pack Wpack/Wapack (direct-compute);
// blocks 12-13 build bbig[320]; blocks 14-31 zero sub.
// ---------------------------------------------------------------------------
__global__ void setup_kernel(const float* __restrict__ Wq, const float* __restrict__ bq,
                             const float* __restrict__ Wk, const float* __restrict__ bk,
                             const float* __restrict__ Wm, const float* __restrict__ bm,
                             const float* __restrict__ Watt0, const float* __restrict__ prior0,
                             const float* __restrict__ Watt1, const float* __restrict__ prior1,
                             const float* __restrict__ Wmsg0, const float* __restrict__ Wmsg1,
                             const float* __restrict__ Wa,
                             float* __restrict__ bbig,
                             unsigned short* __restrict__ Wpack,
                             unsigned short* __restrict__ Wapack,
                             int4* __restrict__ subzero, int n4) {
    const int b = blockIdx.x, t = threadIdx.x;
    if (b < 12) {
        int p = b * TPB + t;
        if (p >= 48 * 64) return;
        bool isWa = (p >= 40 * 64);
        int pl = isWa ? p - 40 * 64 : p;
        int lane = pl & 63, ctkt = pl >> 6;
        int ct = ctkt >> 1, kt = ctkt & 1;
        int kbase = kt * 32 + (lane >> 4) * 8;
        int col = ct * 16 + (lane & 15);
        unsigned short h[8];
        if (isWa) {
            #pragma unroll
            for (int j = 0; j < 8; j++) h[j] = f2bf(Wa[(size_t)(kbase + j) * 64 + col]);
        } else {
            #pragma unroll
            for (int j = 0; j < 8; j++)
                h[j] = f2bf(wbig_elem(Wq, Wk, Wm, Watt0, Watt1, Wmsg0, Wmsg1,
                                      prior0, prior1, kbase + j, col));
        }
        uint4 pk;
        pk.x = (unsigned)h[0] | ((unsigned)h[1] << 16);
        pk.y = (unsigned)h[2] | ((unsigned)h[3] << 16);
        pk.z = (unsigned)h[4] | ((unsigned)h[5] << 16);
        pk.w = (unsigned)h[6] | ((unsigned)h[7] << 16);
        unsigned short* dst = isWa ? Wapack : Wpack;
        *(uint4*)&dst[(size_t)pl * 8] = pk;
    } else if (b < 14) {
        int col = (b - 12) * TPB + t;
        if (col >= 320) return;
        float v;
        if (col < 64) {
            v = bq[col];
        } else {
            int j = col - 64, set = j >> 6, l = j & 63, h = l >> 3, lc = l & 7;
            const float* bin = (set < 2) ? bk : bm;
            const float* T = (set == 0) ? Watt0 : (set == 1) ? Watt1 : (set == 2) ? Wmsg0 : Wmsg1;
            float scale = (set == 0) ? prior0[h] * RSQRT_C_F
                        : (set == 1) ? prior1[h] * RSQRT_C_F : 1.f;
            float acc = 0.f;
            #pragma unroll
            for (int c = 0; c < 8; c++) acc += bin[h * 8 + c] * T[h * 64 + c * 8 + lc];
            v = acc * scale;
        }
        bbig[col] = v;
    } else {
        int i = (b - 14) * TPB + t;
        int stride = 18 * TPB;
        for (; i < n4; i += stride) subzero[i] = int4{0, 0, 0, 0};
    }
}

// ---------------------------------------------------------------------------
// hist, 4 independent edges per thread. Bucket = (e>>8)&7 matches scatter.
// ---------------------------------------------------------------------------
__global__ void hist_kernel(const int* __restrict__ dst0, const int* __restrict__ dst1,
                            int* __restrict__ sub, int* __restrict__ rank,
                            int E0, int Etot, int N) {
    const int gid = blockIdx.x * TPB + threadIdx.x;
    const int S = gridDim.x * TPB;
    #pragma unroll
    for (int k = 0; k < 4; k++) {
        int e = gid + k * S;
        if (e < Etot) {
            int d = (e < E0) ? dst0[e] : dst1[e - E0];
            d = min(max(d, 0), N - 1);
            rank[e] = atomicAdd(&sub[((e >> 8) & 7) * N + d], 1);
        }
    }
}

// ---- scan1 (sumsub fused): reads sub counts, writes exclusive bases + offsets ----
__global__ void scan1(int* __restrict__ sub, int* __restrict__ offsets,
                      int* __restrict__ blocksums, int n) {
    __shared__ int sums[TPB];
    int b = blockIdx.x, t = threadIdx.x;
    int base = b * 1024 + t * 4;
    int cnt[4];
    #pragma unroll
    for (int i = 0; i < 4; i++) {
        int d = base + i;
        int s = 0;
        if (d < n) {
            #pragma unroll
            for (int bb = 0; bb < 8; bb++) {
                int v = sub[bb * n + d];
                sub[bb * n + d] = s;     // exclusive prefix base
                s += v;
            }
        }
        cnt[i] = s;
    }
    int local = cnt[0] + cnt[1] + cnt[2] + cnt[3];
    sums[t] = local;
    __syncthreads();
    for (int off = 1; off < TPB; off <<= 1) {
        int add = (t >= off) ? sums[t - off] : 0;
        __syncthreads();
        sums[t] += add;
        __syncthreads();
    }
    int excl = sums[t] - local;
    if (base + 0 < n) offsets[base + 0] = excl;
    if (base + 1 < n) offsets[base + 1] = excl + cnt[0];
    if (base + 2 < n) offsets[base + 2] = excl + cnt[0] + cnt[1];
    if (base + 3 < n) offsets[base + 3] = excl + cnt[0] + cnt[1] + cnt[2];
    if (t == TPB - 1) blocksums[b] = sums[TPB - 1];
}

// scan3 with scan2 inlined + fused addoff.
__global__ void scan3(int* __restrict__ offsets, const int* __restrict__ blocksums,
                      int* __restrict__ sub, int n, int Etot, int nb) {
    __shared__ int s[TPB];
    __shared__ int excl[TPB];
    int t = threadIdx.x;
    int v = (t < nb) ? blocksums[t] : 0;
    s[t] = v;
    __syncthreads();
    for (int off = 1; off < TPB; off <<= 1) {
        int add = (t >= off) ? s[t - off] : 0;
        __syncthreads();
        s[t] += add;
        __syncthreads();
    }
    excl[t] = s[t] - v;   // exclusive scan of blocksums
    __syncthreads();
    int i = blockIdx.x * TPB + t;
    if (i < n) {
        int vv = offsets[i] + excl[i >> 10];
        offsets[i] = vv;
        #pragma unroll
        for (int b = 0; b < 8; b++) sub[b * n + i] += vv;
    }
    if (i == n) offsets[n] = Etot;
}

// scatter WITHOUT atomics, 4 edges per thread:
// pos = sub_abs[(e>>8)&7][d] + rank[e]
__global__ void scatter_kernel(const int* __restrict__ src0, const int* __restrict__ dst0,
                               const int* __restrict__ src1, const int* __restrict__ dst1,
                               const int* __restrict__ sub,
                               const int* __restrict__ rank, unsigned* __restrict__ records,
                               int E0, int Etot, int N) {
    const int gid = blockIdx.x * TPB + threadIdx.x;
    const int S = gridDim.x * TPB;
    #pragma unroll
    for (int k = 0; k < 4; k++) {
        int e = gid + k * S;
        if (e < Etot) {
            int s, d, setbit;
            if (e < E0) { s = src0[e]; d = dst0[e]; setbit = 0; }
            else        { s = src1[e - E0]; d = dst1[e - E0]; setbit = 1; }
            d = min(max(d, 0), N - 1);
            int pos = sub[((e >> 8) & 7) * N + d] + rank[e];
            pos = min(max(pos, 0), Etot - 1);
            records[pos] = (unsigned)s | ((unsigned)setbit << 24);
        }
    }
}

// ---------------------------------------------------------------------------
// MFMA projection, 128 rows/block, LDS-staged wide-store epilogue (R19-proven).
// kmbuf8 LINE-PAIRED layout (R18-proven): set s: k at s*128, m at s*128+64.
// ---------------------------------------------------------------------------
__global__ __launch_bounds__(TPB) void proj_mfma(const float* __restrict__ x,
                                                 const unsigned short* __restrict__ Wpack,
                                                 const float* __restrict__ bbig,
                                                 unsigned short* __restrict__ qbuf,
                                                 unsigned char* __restrict__ kmbuf8,
                                                 int N) {
    __shared__ unsigned char ldsb[4][4096];
    const int lane = threadIdx.x & 63;
    const int wv = threadIdx.x >> 6;
    unsigned char* L = ldsb[wv];
    const int rb0 = blockIdx.x * 128 + wv * 16;
    const int rb1 = rb0 + 64;
    const int arow0 = min(rb0 + (lane & 15), N - 1);
    const int arow1 = min(rb1 + (lane & 15), N - 1);
    const int kbase = (lane >> 4) * 8;

    bf16x8 afA[2], afB[2];
    #pragma unroll
    for (int kt = 0; kt < 2; kt++) {
        const float* xp = x + (size_t)arow0 * 64 + kt * 32 + kbase;
        float4 v0 = *(const float4*)xp;
        float4 v1 = *(const float4*)(xp + 4);
        bf16x8 a;
        a[0] = (short)f2bf(v0.x); a[1] = (short)f2bf(v0.y);
        a[2] = (short)f2bf(v0.z); a[3] = (short)f2bf(v0.w);
        a[4] = (short)f2bf(v1.x); a[5] = (short)f2bf(v1.y);
        a[6] = (short)f2bf(v1.z); a[7] = (short)f2bf(v1.w);
        afA[kt] = a;
        const float* xq = x + (size_t)arow1 * 64 + kt * 32 + kbase;
        float4 w0 = *(const float4*)xq;
        float4 w1 = *(const float4*)(xq + 4);
        bf16x8 b;
        b[0] = (short)f2bf(w0.x); b[1] = (short)f2bf(w0.y);
        b[2] = (short)f2bf(w0.z); b[3] = (short)f2bf(w0.w);
        b[4] = (short)f2bf(w1.x); b[5] = (short)f2bf(w1.y);
        b[6] = (short)f2bf(w1.z); b[7] = (short)f2bf(w1.w);
        afB[kt] = b;
    }

    const int colq = lane & 15;
    const int rgrp = (lane >> 4) * 4;
    const int rrow = lane >> 2;      // readback row 0..15
    const int rqt = lane & 3;        // readback quarter 0..3

    for (int g = 0; g < 5; g++) {
        #pragma unroll
        for (int ct4 = 0; ct4 < 4; ct4++) {
            const int ct = g * 4 + ct4;
            bf16x8 b0 = *(const bf16x8*)(Wpack + ((size_t)(ct * 2 + 0) * 64 + lane) * 8);
            bf16x8 b1 = *(const bf16x8*)(Wpack + ((size_t)(ct * 2 + 1) * 64 + lane) * 8);
            f32x4 accA = {0.f, 0.f, 0.f, 0.f};
            accA = __builtin_amdgcn_mfma_f32_16x16x32_bf16(afA[0], b0, accA, 0, 0, 0);
            accA = __builtin_amdgcn_mfma_f32_16x16x32_bf16(afA[1], b1, accA, 0, 0, 0);
            f32x4 accB = {0.f, 0.f, 0.f, 0.f};
            accB = __builtin_amdgcn_mfma_f32_16x16x32_bf16(afB[0], b0, accB, 0, 0, 0);
            accB = __builtin_amdgcn_mfma_f32_16x16x32_bf16(afB[1], b1, accB, 0, 0, 0);
            const float bv = bbig[ct * 16 + colq];
            const int cig = ct4 * 16 + colq;   // col within group (0..63)
            if (g == 0) {
                #pragma unroll
                for (int r = 0; r < 4; r++) {
                    *(unsigned short*)&L[(rgrp + r) * 128 + cig * 2]        = f2bf(accA[r] + bv);
                    *(unsigned short*)&L[2048 + (rgrp + r) * 128 + cig * 2] = f2bf(accB[r] + bv);
                }
            } else {
                #pragma unroll
                for (int r = 0; r < 4; r++) {
                    L[(rgrp + r) * 64 + cig]        = enc8(accA[r] + bv);
                    L[1024 + (rgrp + r) * 64 + cig] = enc8(accB[r] + bv);
                }
            }
        }
        __syncthreads();
        if (g == 0) {
            #pragma unroll
            for (int s = 0; s < 2; s++) {
                int row = (s ? rb1 : rb0) + rrow;
                if (row < N) {
                    uint4 v0 = *(const uint4*)&L[s * 2048 + rrow * 128 + rqt * 32];
                    uint4 v1 = *(const uint4*)&L[s * 2048 + rrow * 128 + rqt * 32 + 16];
                    unsigned char* dst = (unsigned char*)qbuf + (size_t)row * 128 + rqt * 32;
                    *(uint4*)dst = v0;
                    *(uint4*)(dst + 16) = v1;
                }
            }
        } else {
            const int gg = g - 1;                              // 0:k0 1:k1 2:m0 3:m1
            const int gbase = (gg & 1) * 128 + (gg >> 1) * 64; // line-paired plane base
            #pragma unroll
            for (int s = 0; s < 2; s++) {
                int row = (s ? rb1 : rb0) + rrow;
                if (row < N) {
                    uint4 v = *(const uint4*)&L[s * 1024 + rrow * 64 + rqt * 16];
                    *(uint4*)(kmbuf8 + (size_t)row * 256 + gbase + rqt * 16) = v;
                }
            }
        }
        __syncthreads();
    }
}

// ---------------------------------------------------------------------------
// Pool (fp8, line-paired k||m): one 8-lane group per receiver.
// lane = (g, j). Per edge the 8 lanes read k-64B + m-64B from ONE 128B line.
// No online max (scores O(0.1); fminf guards; softmax shift-invariance).
// ---------------------------------------------------------------------------
__global__ __launch_bounds__(TPB) void pool_kernel(const unsigned short* __restrict__ qbuf,
                                                   const unsigned char* __restrict__ kmbuf8,
                                                   const unsigned* __restrict__ records,
                                                   const int* __restrict__ offsets,
                                                   unsigned short* __restrict__ pooledN,
                                                   int N) {
    const int lane = threadIdx.x & 63;
    const int j = lane & 7;
    const int r = ((blockIdx.x * TPB + threadIdx.x) >> 6) * 8 + (lane >> 3);
    if (r >= N) return;
    const int beg = offsets[r], end = offsets[r + 1];

    uint4 qv = *(const uint4*)(qbuf + (size_t)r * 64 + (j << 3));
    float qa0 = loF(qv.x), qa1 = hiF(qv.x), qa2 = loF(qv.y), qa3 = hiF(qv.y);
    float qa4 = loF(qv.z), qa5 = hiF(qv.z), qa6 = loF(qv.w), qa7 = hiF(qv.w);

    float d_run = 0.f;
    float p0 = 0.f, p1 = 0.f, p2 = 0.f, p3 = 0.f, p4 = 0.f, p5 = 0.f, p6 = 0.f, p7 = 0.f;

#define EDGE(T) {                                                              \
        unsigned rec = records[T];                                             \
        size_t base = ((size_t)(rec & 0xFFFFFFu) << 8) + (((rec >> 24) & 1u) << 7) + (j << 3); \
        uint2 kv = *(const uint2*)(kmbuf8 + base);                             \
        uint2 mv = *(const uint2*)(kmbuf8 + base + 64);                        \
        float kf[8], mf[8];                                                    \
        dec8x8(kv, kf); dec8x8(mv, mf);                                        \
        float s = kf[0] * qa0 + kf[1] * qa1 + kf[2] * qa2 + kf[3] * qa3        \
                + kf[4] * qa4 + kf[5] * qa5 + kf[6] * qa6 + kf[7] * qa7;       \
        float c = __expf(fminf(s, 60.f));                                      \
        d_run += c;                                                            \
        p0 += c * mf[0]; p1 += c * mf[1]; p2 += c * mf[2]; p3 += c * mf[3];    \
        p4 += c * mf[4]; p5 += c * mf[5]; p6 += c * mf[6]; p7 += c * mf[7];    \
    }

    int t = beg;
    for (; t + 1 < end; t += 2) { EDGE(t); EDGE(t + 1); }
    if (t < end) EDGE(t);
#undef EDGE

    const float inv = (end > beg) ? 1.f / d_run : 0.f;
    uint4 ov;
    ov.x = (unsigned)f2bf(p0 * inv) | ((unsigned)f2bf(p1 * inv) << 16);
    ov.y = (unsigned)f2bf(p2 * inv) | ((unsigned)f2bf(p3 * inv) << 16);
    ov.z = (unsigned)f2bf(p4 * inv) | ((unsigned)f2bf(p5 * inv) << 16);
    ov.w = (unsigned)f2bf(p6 * inv) | ((unsigned)f2bf(p7 * inv) << 16);
    *(uint4*)(pooledN + (size_t)r * 64 + (j << 3)) = ov;
}

// ---------------------------------------------------------------------------
// MFMA final, 64 rows/block (R18 version — latency-bound, needs the larger
// grid; the 128-row B-reuse transform regressed it to 47us at 24% occupancy):
// out = LN( sc*(gelu(pooledN) @ Wa + ba) + (1-sc)*x ).
// ---------------------------------------------------------------------------
__global__ __launch_bounds__(TPB) void final_mfma(const float* __restrict__ x,
                                                  const unsigned short* __restrict__ pooledN,
                                                  const unsigned short* __restrict__ Wapack,
                                                  const float* __restrict__ ba,
                                                  const float* __restrict__ skipw,
                                                  const float* __restrict__ gamma,
                                                  const float* __restrict__ beta,
                                                  float* __restrict__ out, int N) {
    const int lane = threadIdx.x & 63;
    const int wv = threadIdx.x >> 6;
    const int rowbase = blockIdx.x * 64 + wv * 16;
    const int arow = min(rowbase + (lane & 15), N - 1);
    const int kbase = (lane >> 4) * 8;
    const float sc = 1.f / (1.f + __expf(-skipw[0]));

    bf16x8 afrag[2];
    #pragma unroll
    for (int kt = 0; kt < 2; kt++) {
        uint4 pv = *(const uint4*)(pooledN + (size_t)arow * 64 + kt * 32 + kbase);
        float g[8];
        g[0] = loF(pv.x); g[1] = bf2f((unsigned short)(pv.x >> 16));
        g[2] = loF(pv.y); g[3] = bf2f((unsigned short)(pv.y >> 16));
        g[4] = loF(pv.z); g[5] = bf2f((unsigned short)(pv.z >> 16));
        g[6] = loF(pv.w); g[7] = bf2f((unsigned short)(pv.w >> 16));
        bf16x8 a;
        #pragma unroll
        for (int i = 0; i < 8; i++) {
            float gg = 0.5f * g[i] * (1.f + erff(g[i] * 0.70710678118654752f));
            a[i] = (short)f2bf(gg);
        }
        afrag[kt] = a;
    }

    const int colq = lane & 15;
    const int rgrp = (lane >> 4) * 4;

    float o[4][4];   // [ct][r] post-skip values
    #pragma unroll
    for (int ct = 0; ct < 4; ct++) {
        bf16x8 b0 = *(const bf16x8*)(Wapack + ((size_t)(ct * 2 + 0) * 64 + lane) * 8);
        bf16x8 b1 = *(const bf16x8*)(Wapack + ((size_t)(ct * 2 + 1) * 64 + lane) * 8);
        f32x4 acc = {0.f, 0.f, 0.f, 0.f};
        acc = __builtin_amdgcn_mfma_f32_16x16x32_bf16(afrag[0], b0, acc, 0, 0, 0);
        acc = __builtin_amdgcn_mfma_f32_16x16x32_bf16(afrag[1], b1, acc, 0, 0, 0);
        const int col = ct * 16 + colq;
        const float bav = ba[col];
        #pragma unroll
        for (int r = 0; r < 4; r++) {
            int row = min(rowbase + rgrp + r, N - 1);
            float xv = x[(size_t)row * 64 + col];
            o[ct][r] = sc * (acc[r] + bav) + (1.f - sc) * xv;
        }
    }

    #pragma unroll
    for (int r = 0; r < 4; r++) {
        float s1 = o[0][r] + o[1][r] + o[2][r] + o[3][r];
        float s2 = o[0][r] * o[0][r] + o[1][r] * o[1][r]
                 + o[2][r] * o[2][r] + o[3][r] * o[3][r];
        #pragma unroll
        for (int off = 1; off <= 8; off <<= 1) {
            s1 += __shfl_xor(s1, off, 64);
            s2 += __shfl_xor(s2, off, 64);
        }
        float mu = s1 * (1.f / 64.f);
        float var = s2 * (1.f / 64.f) - mu * mu;
        float rs = rsqrtf(var + 1e-3f);
        const int row = rowbase + rgrp + r;
        if (row < N) {
            #pragma unroll
            for (int ct = 0; ct < 4; ct++) {
                const int col = ct * 16 + colq;
                out[(size_t)row * 64 + col] = gamma[col] * (o[ct][r] - mu) * rs + beta[col];
            }
        }
    }
}

extern "C" void kernel_launch(void* const* d_in, const int* in_sizes, int n_in,
                              void* d_out, int out_size, void* d_ws, size_t ws_size,
                              hipStream_t stream) {
    const float* x      = (const float*)d_in[0];
    const int*   src0   = (const int*)d_in[1];
    const int*   dst0   = (const int*)d_in[2];
    const int*   src1   = (const int*)d_in[3];
    const int*   dst1   = (const int*)d_in[4];
    const float* Wk     = (const float*)d_in[5];
    const float* bk     = (const float*)d_in[6];
    const float* Wm     = (const float*)d_in[7];
    const float* bm     = (const float*)d_in[8];
    const float* Wq     = (const float*)d_in[9];
    const float* bq     = (const float*)d_in[10];
    const float* Wa     = (const float*)d_in[11];
    const float* ba     = (const float*)d_in[12];
    const float* Watt0  = (const float*)d_in[13];
    const float* Wmsg0  = (const float*)d_in[14];
    const float* prior0 = (const float*)d_in[15];
    const float* Watt1  = (const float*)d_in[16];
    const float* Wmsg1  = (const float*)d_in[17];
    const float* prior1 = (const float*)d_in[18];
    const float* skipw  = (const float*)d_in[19];
    const float* gamma  = (const float*)d_in[20];
    const float* beta   = (const float*)d_in[21];

    const int N  = in_sizes[0] / 64;
    const int E0 = in_sizes[1];
    const int E1 = in_sizes[3];
    const int Etot = E0 + E1;

    // workspace layout
    float* ws       = (float*)d_ws;
    float* bbig     = ws;                                   // 320 f32
    unsigned short* Wpack  = (unsigned short*)(bbig + 320); // 40*64*8 bf16 (40 KB)
    unsigned short* Wapack = Wpack + 40 * 64 * 8;           // 8*64*8 bf16 (8 KB)
    unsigned short* qbuf   = Wapack + 8 * 64 * 8;           // N*64 bf16
    unsigned short* pooledN = qbuf + (size_t)N * 64;        // N*64 bf16
    unsigned char* kmbuf8  = (unsigned char*)(pooledN + (size_t)N * 64);  // N*256 fp8
    int* sub        = (int*)(kmbuf8 + (size_t)N * 256);     // 8*N (counts -> abs bases)
    int* offsets    = sub + (size_t)8 * N;                  // N+1
    int* blocksums  = offsets + N + 1;                      // <=256
    int* rank       = blocksums + 512;                      // Etot
    unsigned* records = (unsigned*)(rank + Etot);           // Etot

    const int nb1 = (N + 1023) / 1024;                      // <=98 for N=100K
    const int gE4 = (Etot + 4 * TPB - 1) / (4 * TPB);       // 4 edges per thread

    setup_kernel<<<32, TPB, 0, stream>>>(Wq, bq, Wk, bk, Wm, bm, Watt0, prior0,
                                         Watt1, prior1, Wmsg0, Wmsg1, Wa,
                                         bbig, Wpack, Wapack, (int4*)sub, 2 * N);

    proj_mfma<<<(N + 127) / 128, TPB, 0, stream>>>(x, Wpack, bbig, qbuf, kmbuf8, N);

    hist_kernel<<<gE4, TPB, 0, stream>>>(dst0, dst1, sub, rank, E0, Etot, N);

    scan1<<<nb1, TPB, 0, stream>>>(sub, offsets, blocksums, N);
    scan3<<<(N + 1 + TPB - 1) / TPB, TPB, 0, stream>>>(offsets, blocksums, sub, N, Etot, nb1);

    scatter_kernel<<<gE4, TPB, 0, stream>>>(src0, dst0, src1, dst1, sub,
                                            rank, records, E0, Etot, N);

    pool_kernel<<<((size_t)N * 8 + TPB - 1) / TPB, TPB, 0, stream>>>(qbuf, kmbuf8, records,
                                                                     offsets, pooledN, N);

    final_mfma<<<(N + 63) / 64, TPB, 0, stream>>>(x, pooledN, Wapack, ba, skipw,
                                                  gamma, beta, (float*)d_out, N);
}